// Round 3
// baseline (3668.451 us; speedup 1.0000x reference)
//
#include <hip/hip_runtime.h>
#include <hip/hip_bf16.h>

#define NN 50000
#define NE 200000
#define HEADS 4
#define EPSV 1e-5f
#define NEGS 0.01f

using f32x4 = __attribute__((ext_vector_type(4))) float;
using s16x8 = __attribute__((ext_vector_type(8))) short;
using bf16x8 = __attribute__((ext_vector_type(8))) __bf16;

__device__ __forceinline__ short f2bf(float f) {
    union { float f; unsigned u; } v; v.f = f;
    unsigned r = v.u + 0x7FFFu + ((v.u >> 16) & 1u);
    return (short)(r >> 16);
}
__device__ __forceinline__ float bf2f(short s) {
    union { unsigned u; float f; } v; v.u = ((unsigned)(unsigned short)s) << 16;
    return v.f;
}
__device__ __forceinline__ f32x4 mfma16(s16x8 a, s16x8 b, f32x4 c) {
    return __builtin_amdgcn_mfma_f32_16x16x32_bf16(
        __builtin_bit_cast(bf16x8, a), __builtin_bit_cast(bf16x8, b), c, 0, 0, 0);
}
__device__ __forceinline__ void phase_fence() {
    __builtin_amdgcn_wave_barrier();       // compile-time order across phases
    __builtin_amdgcn_sched_barrier(0);     // DS ops are in-order per wave in HW
}

// ---------------- weight prep: fp32 -> bf16, transposed to [col][k] ----------------
__global__ void prep_weights(const float* __restrict__ Kv2v, const float* __restrict__ Vv2v,
                             const float* __restrict__ inpW,
                             const float* __restrict__ Ke2v, const float* __restrict__ Ve2v,
                             const float* __restrict__ luW, const float* __restrict__ msgW,
                             const float* __restrict__ catW,
                             short* __restrict__ nodeW_t, short* __restrict__ KW_t,
                             short* __restrict__ VW_t, short* __restrict__ luW_t,
                             short* __restrict__ msgW_t, short* __restrict__ catW_t)
{
    int i = blockIdx.x * 256 + threadIdx.x;
    if (i < 147456) {                       // nodeW_t [1152][128]
        int j = i >> 7, k = i & 127;
        float v;
        if (j < 512)       v = Kv2v[(j >> 7) * 16384 + k * 128 + (j & 127)];
        else if (j < 1024) v = Vv2v[((j - 512) >> 7) * 16384 + k * 128 + (j & 127)];
        else               v = inpW[k * 128 + (j - 1024)];
        nodeW_t[i] = f2bf(v);
        return;
    }
    i -= 147456;
    if (i < 65536) { int h = i >> 14, rem = i & 16383, col = rem >> 7, k = rem & 127;
        KW_t[i] = f2bf(Ke2v[h * 16384 + k * 128 + col]); return; }
    i -= 65536;
    if (i < 65536) { int h = i >> 14, rem = i & 16383, col = rem >> 7, k = rem & 127;
        VW_t[i] = f2bf(Ve2v[h * 16384 + k * 128 + col]); return; }
    i -= 65536;
    if (i < 262144) { int h = i >> 16, rem = i & 65535, col = rem >> 8, k = rem & 255;
        luW_t[i] = f2bf(luW[h * 65536 + k * 256 + col]); return; }
    i -= 262144;
    if (i < 131072) { int h = i >> 15, rem = i & 32767, col = rem >> 8, k = rem & 255;
        msgW_t[i] = f2bf(msgW[h * 32768 + k * 128 + col]); return; }   // row stride 128!
    i -= 131072;
    if (i < 65536) { int h = i >> 14, rem = i & 16383, col = rem >> 7, k = rem & 127;
        catW_t[i] = f2bf(catW[(h * 128 + k) * 128 + col]); return; }
}

// ---------------- node projections: Kv/Vv (all heads) + residual, one GEMM ----------------
__global__ __launch_bounds__(256, 2)
void node_proj(const float* __restrict__ x, const short* __restrict__ nodeW_t,
               short* __restrict__ Kv_all, short* __restrict__ Vv_all,
               float* __restrict__ resid)
{
    __shared__ alignas(16) short xt[64 * 128];
    const int tid = threadIdx.x;
    const int row0 = blockIdx.x * 64;
    #pragma unroll
    for (int it = 0; it < 8; ++it) {
        int idx4 = it * 256 + tid;
        int r = idx4 >> 5;
        int c = (idx4 & 31) * 4;
        float4 v = {0.f, 0.f, 0.f, 0.f};
        if (row0 + r < NN) v = *(const float4*)(x + (size_t)(row0 + r) * 128 + c);
        short4 sw; sw.x = f2bf(v.x); sw.y = f2bf(v.y); sw.z = f2bf(v.z); sw.w = f2bf(v.w);
        int byte = (r * 256 + c * 2) ^ ((r & 7) << 4);
        *(short4*)((char*)xt + byte) = sw;
    }
    __syncthreads();
    const int lane = tid & 63, w = tid >> 6;
    const int l15 = lane & 15, lg = lane >> 4;
    const int rloc = w * 16 + l15;
    s16x8 a[4];
    #pragma unroll
    for (int ks = 0; ks < 4; ++ks) {
        int byte = (rloc * 256 + (ks * 32 + lg * 8) * 2) ^ ((rloc & 7) << 4);
        a[ks] = *(const s16x8*)((const char*)xt + byte);
    }
    const int rowC = row0 + w * 16 + lg * 4;
    for (int nt = 0; nt < 72; ++nt) {
        int j = nt * 16 + l15;
        f32x4 acc = (f32x4){0.f, 0.f, 0.f, 0.f};
        #pragma unroll
        for (int ks = 0; ks < 4; ++ks)
            acc = mfma16(a[ks], *(const s16x8*)(nodeW_t + j * 128 + ks * 32 + lg * 8), acc);
        #pragma unroll
        for (int r = 0; r < 4; ++r) {
            int row = rowC + r;
            if (row >= NN) continue;
            if (j < 512)       Kv_all[(size_t)row * 512 + j] = f2bf(acc[r]);
            else if (j < 1024) Vv_all[(size_t)row * 512 + (j - 512)] = f2bf(acc[r]);
            else               resid[(size_t)row * 128 + (j - 1024)] = acc[r];
        }
    }
}

// ---------------- fused edge pipeline (barrier-free, per-wave LDS) ----------------
__global__ __launch_bounds__(256, 3)
void edge_kernel(const float* __restrict__ ef, const int* __restrict__ eidx,
                 const short* __restrict__ Kv_all, const short* __restrict__ Vv_all,
                 const short* __restrict__ KW_t, const short* __restrict__ VW_t,
                 const short* __restrict__ luW_t, const short* __restrict__ msgW_t,
                 const short* __restrict__ catW_t,
                 const float* __restrict__ lu_b, const float* __restrict__ ln1_g,
                 const float* __restrict__ ln1_b, const float* __restrict__ msg_b,
                 const float* __restrict__ ln2_g, const float* __restrict__ ln2_b,
                 float* __restrict__ out1)
{
    // per-wave scratch: [0..8191] q rows / k1 rows -> later m1g [16][256]bf16
    //                   [8192..12287] VE / m2 [16][128]bf16
    __shared__ alignas(16) short scratch[4][6144];    // 48 KB total -> 3 blocks/CU
    const int tid = threadIdx.x;
    const int lane = tid & 63, w = tid >> 6;
    const int l15 = lane & 15, lg = lane >> 4;
    const int e0 = blockIdx.x * 64 + w * 16;
    const int rb = lg * 4;
    char* myscr = (char*)scratch[w];
    const float scale = 0.0625f;   // 1/sqrt(2*OUT)

    // A-fragments of edge_feature for this wave's 16 edges (rows e0+l15)
    const float* efr = ef + (size_t)(e0 + l15) * 128 + lg * 8;
    s16x8 aef[4];
    #pragma unroll
    for (int ks = 0; ks < 4; ++ks) {
        float4 v0 = *(const float4*)(efr + ks * 32);
        float4 v1 = *(const float4*)(efr + ks * 32 + 4);
        s16x8 t;
        t[0] = f2bf(v0.x); t[1] = f2bf(v0.y); t[2] = f2bf(v0.z); t[3] = f2bf(v0.w);
        t[4] = f2bf(v1.x); t[5] = f2bf(v1.y); t[6] = f2bf(v1.z); t[7] = f2bf(v1.w);
        aef[ks] = t;
    }

    const int srcA = eidx[e0 + l15];
    int srcC[4], dstC[4];
    #pragma unroll
    for (int r = 0; r < 4; ++r) {
        srcC[r] = eidx[e0 + rb + r];
        dstC[r] = eidx[NE + e0 + rb + r];
    }
    // gather-staging assignment: 4 lanes per edge row
    const int gRow = lane >> 2;            // 0..15
    const int gChunk = lane & 3;           // 0..3 (64B each)
    const int dstG = eidx[NE + e0 + gRow];
    const int srcG = eidx[e0 + gRow];

    f32x4 outc[8];
    #pragma unroll
    for (int nt = 0; nt < 8; ++nt) outc[nt] = (f32x4){0.f, 0.f, 0.f, 0.f};

    for (int h = 0; h < HEADS; ++h) {
        // ---- issue q/k1 gathers early (latency hidden under stage A MFMAs) ----
        s16x8 qv[4], kv[4];
        #pragma unroll
        for (int j = 0; j < 4; ++j) {
            qv[j] = *(const s16x8*)(Kv_all + (size_t)dstG * 512 + h * 128 + gChunk * 32 + j * 8);
            kv[j] = *(const s16x8*)(Kv_all + (size_t)srcG * 512 + h * 128 + gChunk * 32 + j * 8);
        }

        // ---- stage A: KE = ef@Ke2v, VE = ef@Ve2v ----
        f32x4 accK[8], accV[8];
        #pragma unroll
        for (int nt = 0; nt < 8; ++nt) { accK[nt] = (f32x4){0,0,0,0}; accV[nt] = (f32x4){0,0,0,0}; }
        #pragma unroll
        for (int ks = 0; ks < 4; ++ks) {
            #pragma unroll
            for (int nt = 0; nt < 8; ++nt) {
                const int wco = (h * 128 + nt * 16 + l15) * 128 + ks * 32 + lg * 8;
                accK[nt] = mfma16(aef[ks], *(const s16x8*)(KW_t + wco), accK[nt]);
                accV[nt] = mfma16(aef[ks], *(const s16x8*)(VW_t + wco), accV[nt]);
            }
        }
        // VE -> scratch @8192 [16][128]
        #pragma unroll
        for (int nt = 0; nt < 8; ++nt) {
            int c = nt * 16 + l15;
            #pragma unroll
            for (int r = 0; r < 4; ++r) {
                int row = rb + r;
                int byte = 8192 + ((row * 256 + c * 2) ^ ((row & 7) << 4));
                *(short*)(myscr + byte) = f2bf(accV[nt][r]);
            }
        }
        // q/k1 rows -> scratch @0 / @4096 [16][128] each
        #pragma unroll
        for (int j = 0; j < 4; ++j) {
            int byte = gRow * 256 + ((((gChunk * 4 + j) * 16)) ^ ((gRow & 7) << 4));
            *(s16x8*)(myscr + byte) = qv[j];
            *(s16x8*)(myscr + 4096 + byte) = kv[j];
        }
        phase_fence();

        // ---- preload Vv[srcA] fragments for stage C (hidden under stage B) ----
        s16x8 vvr[4];
        #pragma unroll
        for (int ks = 0; ks < 4; ++ks)
            vvr[ks] = *(const s16x8*)(Vv_all + (size_t)srcA * 512 + h * 128 + ks * 32 + lg * 8);

        // ---- stage B: alpha = [q*k1, q*KE]*scale -> LN -> sigmoid gate (bf16-packed) ----
        unsigned gpk[16][2];
        #pragma unroll
        for (int r = 0; r < 4; ++r) {
            const int i = rb + r;
            const int swz = (i & 7) << 4;
            float al[16];
            float s = 0.f, s2 = 0.f;
            #pragma unroll
            for (int nt = 0; nt < 8; ++nt) {
                int off = (i * 256 + nt * 32 + l15 * 2) ^ swz;
                float q  = bf2f(*(const short*)(myscr + off));
                float k1 = bf2f(*(const short*)(myscr + 4096 + off));
                float alo = q * k1 * scale;
                float ahi = q * accK[nt][r] * scale;
                al[nt] = alo; al[nt + 8] = ahi;
                s += alo + ahi; s2 += alo * alo + ahi * ahi;
            }
            #pragma unroll
            for (int m = 1; m < 16; m <<= 1) { s += __shfl_xor(s, m); s2 += __shfl_xor(s2, m); }
            float mean = s * (1.f / 256.f);
            float var  = s2 * (1.f / 256.f) - mean * mean;
            float rstd = rsqrtf(var + EPSV);
            #pragma unroll
            for (int i2 = 0; i2 < 16; ++i2) {
                int c = i2 * 16 + l15;
                float z = (al[i2] - mean) * rstd * ln1_g[h * 256 + c] + ln1_b[h * 256 + c];
                float g = 1.f / (1.f + __expf(-z));
                unsigned gb = (unsigned)(unsigned short)f2bf(g);
                if ((r & 1) == 0) gpk[i2][r >> 1] = gb;
                else              gpk[i2][r >> 1] |= gb << 16;
            }
        }
        phase_fence();

        // ---- stage C: m1 = ([Vv_src|VE] @ luW + lu_b) * gate ----
        f32x4 m1[16];
        #pragma unroll
        for (int nt = 0; nt < 16; ++nt) m1[nt] = (f32x4){0,0,0,0};
        #pragma unroll
        for (int ks = 0; ks < 8; ++ks) {
            s16x8 a;
            if (ks < 4) {
                a = vvr[ks];
            } else {
                int byte = 8192 + ((l15 * 256 + ((ks - 4) * 32 + lg * 8) * 2) ^ ((l15 & 7) << 4));
                a = *(const s16x8*)(myscr + byte);
            }
            #pragma unroll
            for (int nt = 0; nt < 16; ++nt) {
                const int wco = (h * 256 + nt * 16 + l15) * 256 + ks * 32 + lg * 8;
                m1[nt] = mfma16(a, *(const s16x8*)(luW_t + wco), m1[nt]);
            }
        }
        // m1g bf16 -> scratch @0 [16][256] (overwrites q/k1; same-wave program order)
        #pragma unroll
        for (int nt = 0; nt < 16; ++nt) {
            int c = nt * 16 + l15;
            float bias = lu_b[h * 256 + c];
            #pragma unroll
            for (int r = 0; r < 4; ++r) {
                float g = bf2f((short)((gpk[nt][r >> 1] >> ((r & 1) * 16)) & 0xFFFFu));
                int row = rb + r;
                int byte = (row * 512 + c * 2) ^ ((row & 7) << 4);
                *(short*)(myscr + byte) = f2bf((m1[nt][r] + bias) * g);
            }
        }
        phase_fence();

        // ---- stage D: m2 = leaky(LN(m1g @ msgW + msg_b)*g2 + b2) ----
        f32x4 m2[8];
        #pragma unroll
        for (int nt = 0; nt < 8; ++nt) m2[nt] = (f32x4){0,0,0,0};
        #pragma unroll
        for (int ks = 0; ks < 8; ++ks) {
            int byte = (l15 * 512 + (ks * 32 + lg * 8) * 2) ^ ((l15 & 7) << 4);
            s16x8 a = *(const s16x8*)(myscr + byte);
            #pragma unroll
            for (int nt = 0; nt < 8; ++nt) {
                const int wco = (h * 128 + nt * 16 + l15) * 256 + ks * 32 + lg * 8;
                m2[nt] = mfma16(a, *(const s16x8*)(msgW_t + wco), m2[nt]);
            }
        }
        float s[4] = {0,0,0,0}, s2[4] = {0,0,0,0};
        #pragma unroll
        for (int nt = 0; nt < 8; ++nt) {
            int c = nt * 16 + l15;
            float bias = msg_b[h * 128 + c];
            #pragma unroll
            for (int r = 0; r < 4; ++r) {
                float v = m2[nt][r] + bias;
                m2[nt][r] = v;
                s[r] += v; s2[r] += v * v;
            }
        }
        #pragma unroll
        for (int m = 1; m < 16; m <<= 1) {
            #pragma unroll
            for (int r = 0; r < 4; ++r) { s[r] += __shfl_xor(s[r], m); s2[r] += __shfl_xor(s2[r], m); }
        }
        float mean[4], rstd[4];
        #pragma unroll
        for (int r = 0; r < 4; ++r) {
            mean[r] = s[r] * (1.f / 128.f);
            float var = s2[r] * (1.f / 128.f) - mean[r] * mean[r];
            rstd[r] = rsqrtf(var + EPSV);
        }
        #pragma unroll
        for (int nt = 0; nt < 8; ++nt) {        // m2 bf16 -> scratch @8192 [16][128]
            int c = nt * 16 + l15;
            float g2 = ln2_g[h * 128 + c], b2 = ln2_b[h * 128 + c];
            #pragma unroll
            for (int r = 0; r < 4; ++r) {
                float v = (m2[nt][r] - mean[r]) * rstd[r] * g2 + b2;
                v = v > 0.f ? v : v * NEGS;
                int row = rb + r;
                int byte = 8192 + ((row * 256 + c * 2) ^ ((row & 7) << 4));
                *(short*)(myscr + byte) = f2bf(v);
            }
        }
        phase_fence();

        // ---- stage E: outc += m2 @ catW_h ----
        #pragma unroll
        for (int ks = 0; ks < 4; ++ks) {
            int byte = 8192 + ((l15 * 256 + (ks * 32 + lg * 8) * 2) ^ ((l15 & 7) << 4));
            s16x8 a = *(const s16x8*)(myscr + byte);
            #pragma unroll
            for (int nt = 0; nt < 8; ++nt) {
                const int wco = (h * 128 + nt * 16 + l15) * 128 + ks * 32 + lg * 8;
                outc[nt] = mfma16(a, *(const s16x8*)(catW_t + wco), outc[nt]);
            }
        }
        phase_fence();   // protect m2 region before next head's VE writes
    }

    // ---- scatter: one 128-wide atomic add per edge ----
    #pragma unroll
    for (int nt = 0; nt < 8; ++nt) {
        int c = nt * 16 + l15;
        #pragma unroll
        for (int r = 0; r < 4; ++r)
            atomicAdd(out1 + (size_t)dstC[r] * 128 + c, outc[nt][r]);
    }
}

// ---------------- BN statistics ----------------
__global__ void bn_stats(const float* __restrict__ out1, const float* __restrict__ cat_b,
                         float* __restrict__ stats)
{
    const int col = threadIdx.x;
    const int r0 = blockIdx.x * 128;
    const float cb = cat_b[col];
    float s = 0.f, s2 = 0.f;
    for (int i = 0; i < 128; ++i) {
        int row = r0 + i;
        if (row < NN) {
            float v = out1[(size_t)row * 128 + col] + cb;
            s += v; s2 += v * v;
        }
    }
    atomicAdd(stats + col, s);
    atomicAdd(stats + 128 + col, s2);
}

// ---------------- finalize: BN + leaky + residual ----------------
__global__ void finalize(const float* __restrict__ out1, const float* __restrict__ resid,
                         const float* __restrict__ stats, const float* __restrict__ cat_b,
                         const float* __restrict__ bn_g, const float* __restrict__ bn_b,
                         const float* __restrict__ inp_b, float* __restrict__ out)
{
    int i = blockIdx.x * 256 + threadIdx.x;
    if (i >= NN * 128) return;
    int col = i & 127;
    float mu = stats[col] * (1.f / NN);
    float var = stats[128 + col] * (1.f / NN) - mu * mu;
    float rstd = rsqrtf(var + EPSV);
    float v = out1[i] + cat_b[col];
    v = (v - mu) * rstd * bn_g[col] + bn_b[col];
    v = v > 0.f ? v : v * NEGS;
    out[i] = v + resid[i] + inp_b[col];
}

extern "C" void kernel_launch(void* const* d_in, const int* in_sizes, int n_in,
                              void* d_out, int out_size, void* d_ws, size_t ws_size,
                              hipStream_t stream)
{
    (void)in_sizes; (void)n_in; (void)out_size; (void)ws_size;
    const float* x     = (const float*)d_in[0];
    const int*   eidx  = (const int*)d_in[1];
    const float* ef    = (const float*)d_in[2];
    const float* Kv2v  = (const float*)d_in[3];
    const float* Ke2v  = (const float*)d_in[4];
    const float* Vv2v  = (const float*)d_in[5];
    const float* Ve2v  = (const float*)d_in[6];
    const float* lu_W  = (const float*)d_in[7];
    const float* lu_b  = (const float*)d_in[8];
    const float* ln1_g = (const float*)d_in[9];
    const float* ln1_b = (const float*)d_in[10];
    const float* msg_W = (const float*)d_in[11];
    const float* msg_b = (const float*)d_in[12];
    const float* ln2_g = (const float*)d_in[13];
    const float* ln2_b = (const float*)d_in[14];
    const float* cat_W = (const float*)d_in[15];
    const float* cat_b = (const float*)d_in[16];
    const float* inp_W = (const float*)d_in[17];
    const float* inp_b = (const float*)d_in[18];
    const float* bn_g  = (const float*)d_in[19];
    const float* bn_b  = (const float*)d_in[20];

    char* ws = (char*)d_ws;
    short* nodeW_t = (short*)(ws + 0);          // 294912
    short* KW_t    = (short*)(ws + 294912);     // 131072
    short* VW_t    = (short*)(ws + 425984);     // 131072
    short* luW_t   = (short*)(ws + 557056);     // 524288
    short* msgW_t  = (short*)(ws + 1081344);    // 262144
    short* catW_t  = (short*)(ws + 1343488);    // 131072
    short* Kv_all  = (short*)(ws + 1474560);    // 51,200,000
    short* Vv_all  = (short*)(ws + 52674560);   // 51,200,000
    float* resid   = (float*)(ws + 103874560);  // 25,600,000
    float* out1    = (float*)(ws + 129474560);  // 25,600,000
    float* stats   = (float*)(ws + 155074560);  // 1024

    hipMemsetAsync(out1, 0, 25600000 + 1024, stream);   // out1 + stats (contiguous)
    prep_weights<<<2880, 256, 0, stream>>>(Kv2v, Vv2v, inp_W, Ke2v, Ve2v, lu_W, msg_W, cat_W,
                                           nodeW_t, KW_t, VW_t, luW_t, msgW_t, catW_t);
    node_proj<<<782, 256, 0, stream>>>(x, nodeW_t, Kv_all, Vv_all, resid);
    edge_kernel<<<3125, 256, 0, stream>>>(ef, eidx, Kv_all, Vv_all, KW_t, VW_t, luW_t,
                                          msgW_t, catW_t, lu_b, ln1_g, ln1_b, msg_b,
                                          ln2_g, ln2_b, out1);
    bn_stats<<<391, 128, 0, stream>>>(out1, cat_b, stats);
    finalize<<<25000, 256, 0, stream>>>(out1, resid, stats, cat_b, bn_g, bn_b, inp_b,
                                        (float*)d_out);
}

// Round 4
// 2891.973 us; speedup vs baseline: 1.2685x; 1.2685x over previous
//
#include <hip/hip_runtime.h>
#include <hip/hip_bf16.h>

#define NN 50000
#define NE 200000
#define HEADS 4
#define EPSV 1e-5f
#define NEGS 0.01f

using f32x4 = __attribute__((ext_vector_type(4))) float;
using s16x8 = __attribute__((ext_vector_type(8))) short;
using bf16x8 = __attribute__((ext_vector_type(8))) __bf16;

__device__ __forceinline__ short f2bf(float f) {
    union { float f; unsigned u; } v; v.f = f;
    unsigned r = v.u + 0x7FFFu + ((v.u >> 16) & 1u);
    return (short)(r >> 16);
}
__device__ __forceinline__ float bf2f(short s) {
    union { unsigned u; float f; } v; v.u = ((unsigned)(unsigned short)s) << 16;
    return v.f;
}
__device__ __forceinline__ f32x4 mfma16(s16x8 a, s16x8 b, f32x4 c) {
    return __builtin_amdgcn_mfma_f32_16x16x32_bf16(
        __builtin_bit_cast(bf16x8, a), __builtin_bit_cast(bf16x8, b), c, 0, 0, 0);
}
__device__ __forceinline__ void phase_fence() {
    __builtin_amdgcn_wave_barrier();
    __builtin_amdgcn_sched_barrier(0);
}

// ---------------- weight prep: fp32 -> bf16, transposed to [col][k] ----------------
__global__ void prep_weights(const float* __restrict__ Kv2v, const float* __restrict__ Vv2v,
                             const float* __restrict__ inpW,
                             const float* __restrict__ Ke2v, const float* __restrict__ Ve2v,
                             const float* __restrict__ luW, const float* __restrict__ msgW,
                             const float* __restrict__ catW,
                             short* __restrict__ nodeW_t, short* __restrict__ KW_t,
                             short* __restrict__ VW_t, short* __restrict__ luW_t,
                             short* __restrict__ msgW_t, short* __restrict__ catW_t)
{
    int i = blockIdx.x * 256 + threadIdx.x;
    if (i < 147456) {                       // nodeW_t [1152][128]
        int j = i >> 7, k = i & 127;
        float v;
        if (j < 512)       v = Kv2v[(j >> 7) * 16384 + k * 128 + (j & 127)];
        else if (j < 1024) v = Vv2v[((j - 512) >> 7) * 16384 + k * 128 + (j & 127)];
        else               v = inpW[k * 128 + (j - 1024)];
        nodeW_t[i] = f2bf(v);
        return;
    }
    i -= 147456;
    if (i < 65536) { int h = i >> 14, rem = i & 16383, col = rem >> 7, k = rem & 127;
        KW_t[i] = f2bf(Ke2v[h * 16384 + k * 128 + col]); return; }
    i -= 65536;
    if (i < 65536) { int h = i >> 14, rem = i & 16383, col = rem >> 7, k = rem & 127;
        VW_t[i] = f2bf(Ve2v[h * 16384 + k * 128 + col]); return; }
    i -= 65536;
    if (i < 262144) { int h = i >> 16, rem = i & 65535, col = rem >> 8, k = rem & 255;
        luW_t[i] = f2bf(luW[h * 65536 + k * 256 + col]); return; }
    i -= 262144;
    if (i < 131072) { int h = i >> 15, rem = i & 32767, col = rem >> 8, k = rem & 255;
        msgW_t[i] = f2bf(msgW[h * 32768 + k * 128 + col]); return; }   // row stride 128!
    i -= 131072;
    if (i < 65536) { int h = i >> 14, rem = i & 16383, col = rem >> 7, k = rem & 127;
        catW_t[i] = f2bf(catW[(h * 128 + k) * 128 + col]); return; }
}

// ---------------- node projections: Kv/Vv (all heads) + residual, one GEMM ----------------
__global__ __launch_bounds__(256, 2)
void node_proj(const float* __restrict__ x, const short* __restrict__ nodeW_t,
               short* __restrict__ Kv_all, short* __restrict__ Vv_all,
               float* __restrict__ resid)
{
    __shared__ alignas(16) short xt[64 * 128];
    const int tid = threadIdx.x;
    const int row0 = blockIdx.x * 64;
    #pragma unroll
    for (int it = 0; it < 8; ++it) {
        int idx4 = it * 256 + tid;
        int r = idx4 >> 5;
        int c = (idx4 & 31) * 4;
        float4 v = {0.f, 0.f, 0.f, 0.f};
        if (row0 + r < NN) v = *(const float4*)(x + (size_t)(row0 + r) * 128 + c);
        short4 sw; sw.x = f2bf(v.x); sw.y = f2bf(v.y); sw.z = f2bf(v.z); sw.w = f2bf(v.w);
        int byte = (r * 256 + c * 2) ^ ((r & 7) << 4);
        *(short4*)((char*)xt + byte) = sw;
    }
    __syncthreads();
    const int lane = tid & 63, w = tid >> 6;
    const int l15 = lane & 15, lg = lane >> 4;
    const int rloc = w * 16 + l15;
    s16x8 a[4];
    #pragma unroll
    for (int ks = 0; ks < 4; ++ks) {
        int byte = (rloc * 256 + (ks * 32 + lg * 8) * 2) ^ ((rloc & 7) << 4);
        a[ks] = *(const s16x8*)((const char*)xt + byte);
    }
    const int rowC = row0 + w * 16 + lg * 4;
    for (int nc = 0; nc < 18; ++nc) {        // 72 output-col tiles, chunks of 4 for MLP
        f32x4 acc[4];
        s16x8 b[16];
        #pragma unroll
        for (int q = 0; q < 4; ++q) {
            acc[q] = (f32x4){0.f, 0.f, 0.f, 0.f};
            int j = (nc * 4 + q) * 16 + l15;
            #pragma unroll
            for (int ks = 0; ks < 4; ++ks)
                b[q * 4 + ks] = *(const s16x8*)(nodeW_t + j * 128 + ks * 32 + lg * 8);
        }
        #pragma unroll
        for (int q = 0; q < 4; ++q)
            #pragma unroll
            for (int ks = 0; ks < 4; ++ks)
                acc[q] = mfma16(a[ks], b[q * 4 + ks], acc[q]);
        #pragma unroll
        for (int q = 0; q < 4; ++q) {
            int j = (nc * 4 + q) * 16 + l15;
            #pragma unroll
            for (int r = 0; r < 4; ++r) {
                int row = rowC + r;
                if (row >= NN) continue;
                if (j < 512)       Kv_all[(size_t)row * 512 + j] = f2bf(acc[q][r]);
                else if (j < 1024) Vv_all[(size_t)row * 512 + (j - 512)] = f2bf(acc[q][r]);
                else               resid[(size_t)row * 128 + (j - 1024)] = acc[q][r];
            }
        }
    }
}

// ---------------- fused edge pipeline (barrier-free, per-wave LDS, 8-deep B-prefetch) ----------------
__global__ __launch_bounds__(256, 2)
void edge_kernel(const float* __restrict__ ef, const int* __restrict__ eidx,
                 const short* __restrict__ Kv_all, const short* __restrict__ Vv_all,
                 const short* __restrict__ KW_t, const short* __restrict__ VW_t,
                 const short* __restrict__ luW_t, const short* __restrict__ msgW_t,
                 const short* __restrict__ catW_t,
                 const float* __restrict__ lu_b, const float* __restrict__ ln1_g,
                 const float* __restrict__ ln1_b, const float* __restrict__ msg_b,
                 const float* __restrict__ ln2_g, const float* __restrict__ ln2_b,
                 float* __restrict__ out1)
{
    // per-wave scratch: [0..8191] q rows / k1 rows -> later m1g [16][256]bf16
    //                   [8192..12287] VE / m2 [16][128]bf16
    __shared__ alignas(16) short scratch[4][6144];    // 48 KB total
    const int tid = threadIdx.x;
    const int lane = tid & 63, w = tid >> 6;
    const int l15 = lane & 15, lg = lane >> 4;
    const int e0 = blockIdx.x * 64 + w * 16;
    const int rb = lg * 4;
    char* myscr = (char*)scratch[w];
    const float scale = 0.0625f;   // 1/sqrt(2*OUT)

    // A-fragments of edge_feature for this wave's 16 edges (rows e0+l15)
    const float* efr = ef + (size_t)(e0 + l15) * 128 + lg * 8;
    s16x8 aef[4];
    #pragma unroll
    for (int ks = 0; ks < 4; ++ks) {
        float4 v0 = *(const float4*)(efr + ks * 32);
        float4 v1 = *(const float4*)(efr + ks * 32 + 4);
        s16x8 t;
        t[0] = f2bf(v0.x); t[1] = f2bf(v0.y); t[2] = f2bf(v0.z); t[3] = f2bf(v0.w);
        t[4] = f2bf(v1.x); t[5] = f2bf(v1.y); t[6] = f2bf(v1.z); t[7] = f2bf(v1.w);
        aef[ks] = t;
    }

    const int srcA = eidx[e0 + l15];
    int dstC[4];
    #pragma unroll
    for (int r = 0; r < 4; ++r)
        dstC[r] = eidx[NE + e0 + rb + r];
    // gather-staging assignment: 4 lanes per edge row
    const int gRow = lane >> 2;            // 0..15
    const int gChunk = lane & 3;           // 0..3 (64B each)
    const int dstG = eidx[NE + e0 + gRow];
    const int srcG = eidx[e0 + gRow];

    f32x4 outc[8];
    #pragma unroll
    for (int nt = 0; nt < 8; ++nt) outc[nt] = (f32x4){0.f, 0.f, 0.f, 0.f};

    for (int h = 0; h < HEADS; ++h) {
        // ---- issue q/k1 gathers early (latency hidden under stage A MFMAs) ----
        s16x8 qv[4], kv[4];
        #pragma unroll
        for (int j = 0; j < 4; ++j) {
            qv[j] = *(const s16x8*)(Kv_all + (size_t)dstG * 512 + h * 128 + gChunk * 32 + j * 8);
            kv[j] = *(const s16x8*)(Kv_all + (size_t)srcG * 512 + h * 128 + gChunk * 32 + j * 8);
        }

        // ---- stage A: KE = ef@Ke2v, VE = ef@Ve2v (8-deep B groups) ----
        f32x4 accK[8], accV[8];
        #pragma unroll
        for (int nt = 0; nt < 8; ++nt) { accK[nt] = (f32x4){0,0,0,0}; accV[nt] = (f32x4){0,0,0,0}; }
        #pragma unroll
        for (int ks = 0; ks < 4; ++ks) {
            const short* wK = KW_t + (size_t)(h * 128 + l15) * 128 + ks * 32 + lg * 8;
            const short* wV = VW_t + (size_t)(h * 128 + l15) * 128 + ks * 32 + lg * 8;
            s16x8 b[8];
            #pragma unroll
            for (int j = 0; j < 8; ++j) b[j] = *(const s16x8*)(wK + j * 16 * 128);
            #pragma unroll
            for (int j = 0; j < 8; ++j) accK[j] = mfma16(aef[ks], b[j], accK[j]);
            #pragma unroll
            for (int j = 0; j < 8; ++j) b[j] = *(const s16x8*)(wV + j * 16 * 128);
            #pragma unroll
            for (int j = 0; j < 8; ++j) accV[j] = mfma16(aef[ks], b[j], accV[j]);
        }
        // VE -> scratch @8192 [16][128]
        #pragma unroll
        for (int nt = 0; nt < 8; ++nt) {
            int c = nt * 16 + l15;
            #pragma unroll
            for (int r = 0; r < 4; ++r) {
                int row = rb + r;
                int byte = 8192 + ((row * 256 + c * 2) ^ ((row & 7) << 4));
                *(short*)(myscr + byte) = f2bf(accV[nt][r]);
            }
        }
        // q/k1 rows -> scratch @0 / @4096 [16][128] each
        #pragma unroll
        for (int j = 0; j < 4; ++j) {
            int byte = gRow * 256 + ((((gChunk * 4 + j) * 16)) ^ ((gRow & 7) << 4));
            *(s16x8*)(myscr + byte) = qv[j];
            *(s16x8*)(myscr + 4096 + byte) = kv[j];
        }
        phase_fence();

        // ---- preload Vv[srcA] fragments for stage C (hidden under stage B) ----
        s16x8 vvr[4];
        #pragma unroll
        for (int ks = 0; ks < 4; ++ks)
            vvr[ks] = *(const s16x8*)(Vv_all + (size_t)srcA * 512 + h * 128 + ks * 32 + lg * 8);

        // ---- stage B: alpha = [q*k1, q*KE]*scale -> LN -> sigmoid gate (bf16-packed) ----
        unsigned gpk[16][2];
        #pragma unroll
        for (int r = 0; r < 4; ++r) {
            const int i = rb + r;
            const int swz = (i & 7) << 4;
            float al[16];
            float s = 0.f, s2 = 0.f;
            #pragma unroll
            for (int nt = 0; nt < 8; ++nt) {
                int off = (i * 256 + nt * 32 + l15 * 2) ^ swz;
                float q  = bf2f(*(const short*)(myscr + off));
                float k1 = bf2f(*(const short*)(myscr + 4096 + off));
                float alo = q * k1 * scale;
                float ahi = q * accK[nt][r] * scale;
                al[nt] = alo; al[nt + 8] = ahi;
                s += alo + ahi; s2 += alo * alo + ahi * ahi;
            }
            #pragma unroll
            for (int m = 1; m < 16; m <<= 1) { s += __shfl_xor(s, m); s2 += __shfl_xor(s2, m); }
            float mean = s * (1.f / 256.f);
            float var  = s2 * (1.f / 256.f) - mean * mean;
            float rstd = rsqrtf(var + EPSV);
            #pragma unroll
            for (int i2 = 0; i2 < 16; ++i2) {
                int c = i2 * 16 + l15;
                float z = (al[i2] - mean) * rstd * ln1_g[h * 256 + c] + ln1_b[h * 256 + c];
                float g = 1.f / (1.f + __expf(-z));
                unsigned gb = (unsigned)(unsigned short)f2bf(g);
                if ((r & 1) == 0) gpk[i2][r >> 1] = gb;
                else              gpk[i2][r >> 1] |= gb << 16;
            }
        }
        phase_fence();

        // ---- stage C: m1 = ([Vv_src|VE] @ luW + lu_b) * gate (8-deep B groups) ----
        f32x4 m1[16];
        #pragma unroll
        for (int nt = 0; nt < 16; ++nt) m1[nt] = (f32x4){0,0,0,0};
        #pragma unroll
        for (int ks = 0; ks < 8; ++ks) {
            s16x8 a;
            if (ks < 4) {
                a = vvr[ks];
            } else {
                int byte = 8192 + ((l15 * 256 + ((ks - 4) * 32 + lg * 8) * 2) ^ ((l15 & 7) << 4));
                a = *(const s16x8*)(myscr + byte);
            }
            const short* wb = luW_t + (size_t)(h * 256 + l15) * 256 + ks * 32 + lg * 8;
            s16x8 b[8];
            #pragma unroll
            for (int j = 0; j < 8; ++j) b[j] = *(const s16x8*)(wb + j * 16 * 256);
            #pragma unroll
            for (int j = 0; j < 8; ++j) m1[j] = mfma16(a, b[j], m1[j]);
            #pragma unroll
            for (int j = 0; j < 8; ++j) b[j] = *(const s16x8*)(wb + (j + 8) * 16 * 256);
            #pragma unroll
            for (int j = 0; j < 8; ++j) m1[j + 8] = mfma16(a, b[j], m1[j + 8]);
        }
        // m1g bf16 -> scratch @0 [16][256] (overwrites q/k1; same-wave program order)
        #pragma unroll
        for (int nt = 0; nt < 16; ++nt) {
            int c = nt * 16 + l15;
            float bias = lu_b[h * 256 + c];
            #pragma unroll
            for (int r = 0; r < 4; ++r) {
                float g = bf2f((short)((gpk[nt][r >> 1] >> ((r & 1) * 16)) & 0xFFFFu));
                int row = rb + r;
                int byte = (row * 512 + c * 2) ^ ((row & 7) << 4);
                *(short*)(myscr + byte) = f2bf((m1[nt][r] + bias) * g);
            }
        }
        phase_fence();

        // ---- stage D: m2 = leaky(LN(m1g @ msgW + msg_b)*g2 + b2) (8-deep B groups) ----
        f32x4 m2[8];
        #pragma unroll
        for (int nt = 0; nt < 8; ++nt) m2[nt] = (f32x4){0,0,0,0};
        #pragma unroll
        for (int ks = 0; ks < 8; ++ks) {
            int byte = (l15 * 512 + (ks * 32 + lg * 8) * 2) ^ ((l15 & 7) << 4);
            s16x8 a = *(const s16x8*)(myscr + byte);
            const short* wb = msgW_t + (size_t)(h * 128 + l15) * 256 + ks * 32 + lg * 8;
            s16x8 b[8];
            #pragma unroll
            for (int j = 0; j < 8; ++j) b[j] = *(const s16x8*)(wb + j * 16 * 256);
            #pragma unroll
            for (int j = 0; j < 8; ++j) m2[j] = mfma16(a, b[j], m2[j]);
        }
        float s[4] = {0,0,0,0}, s2[4] = {0,0,0,0};
        #pragma unroll
        for (int nt = 0; nt < 8; ++nt) {
            int c = nt * 16 + l15;
            float bias = msg_b[h * 128 + c];
            #pragma unroll
            for (int r = 0; r < 4; ++r) {
                float v = m2[nt][r] + bias;
                m2[nt][r] = v;
                s[r] += v; s2[r] += v * v;
            }
        }
        #pragma unroll
        for (int m = 1; m < 16; m <<= 1) {
            #pragma unroll
            for (int r = 0; r < 4; ++r) { s[r] += __shfl_xor(s[r], m); s2[r] += __shfl_xor(s2[r], m); }
        }
        float mean[4], rstd[4];
        #pragma unroll
        for (int r = 0; r < 4; ++r) {
            mean[r] = s[r] * (1.f / 128.f);
            float var = s2[r] * (1.f / 128.f) - mean[r] * mean[r];
            rstd[r] = rsqrtf(var + EPSV);
        }
        #pragma unroll
        for (int nt = 0; nt < 8; ++nt) {        // m2 bf16 -> scratch @8192 [16][128]
            int c = nt * 16 + l15;
            float g2 = ln2_g[h * 128 + c], b2 = ln2_b[h * 128 + c];
            #pragma unroll
            for (int r = 0; r < 4; ++r) {
                float v = (m2[nt][r] - mean[r]) * rstd[r] * g2 + b2;
                v = v > 0.f ? v : v * NEGS;
                int row = rb + r;
                int byte = 8192 + ((row * 256 + c * 2) ^ ((row & 7) << 4));
                *(short*)(myscr + byte) = f2bf(v);
            }
        }
        phase_fence();

        // ---- stage E: outc += m2 @ catW_h (8-deep B groups) ----
        #pragma unroll
        for (int ks = 0; ks < 4; ++ks) {
            int byte = 8192 + ((l15 * 256 + (ks * 32 + lg * 8) * 2) ^ ((l15 & 7) << 4));
            s16x8 a = *(const s16x8*)(myscr + byte);
            const short* wb = catW_t + (size_t)(h * 128 + l15) * 128 + ks * 32 + lg * 8;
            s16x8 b[8];
            #pragma unroll
            for (int j = 0; j < 8; ++j) b[j] = *(const s16x8*)(wb + j * 16 * 128);
            #pragma unroll
            for (int j = 0; j < 8; ++j) outc[j] = mfma16(a, b[j], outc[j]);
        }
        phase_fence();   // protect m2 region before next head's VE writes
    }

    // ---- scatter: one 128-wide atomic add per edge ----
    #pragma unroll
    for (int nt = 0; nt < 8; ++nt) {
        int c = nt * 16 + l15;
        #pragma unroll
        for (int r = 0; r < 4; ++r)
            atomicAdd(out1 + (size_t)dstC[r] * 128 + c, outc[nt][r]);
    }
}

// ---------------- BN statistics ----------------
__global__ void bn_stats(const float* __restrict__ out1, const float* __restrict__ cat_b,
                         float* __restrict__ stats)
{
    const int col = threadIdx.x;
    const int r0 = blockIdx.x * 128;
    const float cb = cat_b[col];
    float s = 0.f, s2 = 0.f;
    for (int i = 0; i < 128; ++i) {
        int row = r0 + i;
        if (row < NN) {
            float v = out1[(size_t)row * 128 + col] + cb;
            s += v; s2 += v * v;
        }
    }
    atomicAdd(stats + col, s);
    atomicAdd(stats + 128 + col, s2);
}

// ---------------- finalize: BN + leaky + residual ----------------
__global__ void finalize(const float* __restrict__ out1, const float* __restrict__ resid,
                         const float* __restrict__ stats, const float* __restrict__ cat_b,
                         const float* __restrict__ bn_g, const float* __restrict__ bn_b,
                         const float* __restrict__ inp_b, float* __restrict__ out)
{
    int i = blockIdx.x * 256 + threadIdx.x;
    if (i >= NN * 128) return;
    int col = i & 127;
    float mu = stats[col] * (1.f / NN);
    float var = stats[128 + col] * (1.f / NN) - mu * mu;
    float rstd = rsqrtf(var + EPSV);
    float v = out1[i] + cat_b[col];
    v = (v - mu) * rstd * bn_g[col] + bn_b[col];
    v = v > 0.f ? v : v * NEGS;
    out[i] = v + resid[i] + inp_b[col];
}

extern "C" void kernel_launch(void* const* d_in, const int* in_sizes, int n_in,
                              void* d_out, int out_size, void* d_ws, size_t ws_size,
                              hipStream_t stream)
{
    (void)in_sizes; (void)n_in; (void)out_size; (void)ws_size;
    const float* x     = (const float*)d_in[0];
    const int*   eidx  = (const int*)d_in[1];
    const float* ef    = (const float*)d_in[2];
    const float* Kv2v  = (const float*)d_in[3];
    const float* Ke2v  = (const float*)d_in[4];
    const float* Vv2v  = (const float*)d_in[5];
    const float* Ve2v  = (const float*)d_in[6];
    const float* lu_W  = (const float*)d_in[7];
    const float* lu_b  = (const float*)d_in[8];
    const float* ln1_g = (const float*)d_in[9];
    const float* ln1_b = (const float*)d_in[10];
    const float* msg_W = (const float*)d_in[11];
    const float* msg_b = (const float*)d_in[12];
    const float* ln2_g = (const float*)d_in[13];
    const float* ln2_b = (const float*)d_in[14];
    const float* cat_W = (const float*)d_in[15];
    const float* cat_b = (const float*)d_in[16];
    const float* inp_W = (const float*)d_in[17];
    const float* inp_b = (const float*)d_in[18];
    const float* bn_g  = (const float*)d_in[19];
    const float* bn_b  = (const float*)d_in[20];

    char* ws = (char*)d_ws;
    short* nodeW_t = (short*)(ws + 0);          // 294912
    short* KW_t    = (short*)(ws + 294912);     // 131072
    short* VW_t    = (short*)(ws + 425984);     // 131072
    short* luW_t   = (short*)(ws + 557056);     // 524288
    short* msgW_t  = (short*)(ws + 1081344);    // 262144
    short* catW_t  = (short*)(ws + 1343488);    // 131072
    short* Kv_all  = (short*)(ws + 1474560);    // 51,200,000
    short* Vv_all  = (short*)(ws + 52674560);   // 51,200,000
    float* resid   = (float*)(ws + 103874560);  // 25,600,000
    float* out1    = (float*)(ws + 129474560);  // 25,600,000
    float* stats   = (float*)(ws + 155074560);  // 1024

    hipMemsetAsync(out1, 0, 25600000 + 1024, stream);   // out1 + stats (contiguous)
    prep_weights<<<2880, 256, 0, stream>>>(Kv2v, Vv2v, inp_W, Ke2v, Ve2v, lu_W, msg_W, cat_W,
                                           nodeW_t, KW_t, VW_t, luW_t, msgW_t, catW_t);
    node_proj<<<782, 256, 0, stream>>>(x, nodeW_t, Kv_all, Vv_all, resid);
    edge_kernel<<<3125, 256, 0, stream>>>(ef, eidx, Kv_all, Vv_all, KW_t, VW_t, luW_t,
                                          msgW_t, catW_t, lu_b, ln1_g, ln1_b, msg_b,
                                          ln2_g, ln2_b, out1);
    bn_stats<<<391, 128, 0, stream>>>(out1, cat_b, stats);
    finalize<<<25000, 256, 0, stream>>>(out1, resid, stats, cat_b, bn_g, bn_b, inp_b,
                                        (float*)d_out);
}

// Round 5
// 2430.196 us; speedup vs baseline: 1.5095x; 1.1900x over previous
//
#include <hip/hip_runtime.h>
#include <hip/hip_bf16.h>

#define NN 50000
#define NE 200000
#define HEADS 4
#define EPSV 1e-5f
#define NEGS 0.01f

using f32x4 = __attribute__((ext_vector_type(4))) float;
using s16x8 = __attribute__((ext_vector_type(8))) short;
using bf16x8 = __attribute__((ext_vector_type(8))) __bf16;

__device__ __forceinline__ short f2bf(float f) {
    union { float f; unsigned u; } v; v.f = f;
    unsigned r = v.u + 0x7FFFu + ((v.u >> 16) & 1u);
    return (short)(r >> 16);
}
__device__ __forceinline__ float bf2f(short s) {
    union { unsigned u; float f; } v; v.u = ((unsigned)(unsigned short)s) << 16;
    return v.f;
}
__device__ __forceinline__ f32x4 mfma16(s16x8 a, s16x8 b, f32x4 c) {
    return __builtin_amdgcn_mfma_f32_16x16x32_bf16(
        __builtin_bit_cast(bf16x8, a), __builtin_bit_cast(bf16x8, b), c, 0, 0, 0);
}

// ---------------- weight prep: fp32 -> bf16, transposed to [col][k] ----------------
__global__ void prep_weights(const float* __restrict__ Kv2v, const float* __restrict__ Vv2v,
                             const float* __restrict__ inpW,
                             const float* __restrict__ Ke2v, const float* __restrict__ Ve2v,
                             const float* __restrict__ luW, const float* __restrict__ msgW,
                             const float* __restrict__ catW,
                             short* __restrict__ nodeW_t, short* __restrict__ KW_t,
                             short* __restrict__ VW_t, short* __restrict__ luW_t,
                             short* __restrict__ msgW_t, short* __restrict__ catW_t)
{
    int i = blockIdx.x * 256 + threadIdx.x;
    if (i < 147456) {                       // nodeW_t [1152][128]
        int j = i >> 7, k = i & 127;
        float v;
        if (j < 512)       v = Kv2v[(j >> 7) * 16384 + k * 128 + (j & 127)];
        else if (j < 1024) v = Vv2v[((j - 512) >> 7) * 16384 + k * 128 + (j & 127)];
        else               v = inpW[k * 128 + (j - 1024)];
        nodeW_t[i] = f2bf(v);
        return;
    }
    i -= 147456;
    if (i < 65536) { int h = i >> 14, rem = i & 16383, col = rem >> 7, k = rem & 127;
        KW_t[i] = f2bf(Ke2v[h * 16384 + k * 128 + col]); return; }
    i -= 65536;
    if (i < 65536) { int h = i >> 14, rem = i & 16383, col = rem >> 7, k = rem & 127;
        VW_t[i] = f2bf(Ve2v[h * 16384 + k * 128 + col]); return; }
    i -= 65536;
    if (i < 262144) { int h = i >> 16, rem = i & 65535, col = rem >> 8, k = rem & 255;
        luW_t[i] = f2bf(luW[h * 65536 + k * 256 + col]); return; }
    i -= 262144;
    if (i < 131072) { int h = i >> 15, rem = i & 32767, col = rem >> 8, k = rem & 255;
        msgW_t[i] = f2bf(msgW[h * 32768 + k * 128 + col]); return; }   // row stride 128!
    i -= 131072;
    if (i < 65536) { int h = i >> 14, rem = i & 16383, col = rem >> 7, k = rem & 127;
        catW_t[i] = f2bf(catW[(h * 128 + k) * 128 + col]); return; }
}

// ---------------- node projections: Kv/Vv (all heads) + residual, one GEMM ----------------
__global__ __launch_bounds__(256, 2)
void node_proj(const float* __restrict__ x, const short* __restrict__ nodeW_t,
               short* __restrict__ Kv_all, short* __restrict__ Vv_all,
               float* __restrict__ resid)
{
    __shared__ alignas(16) short xt[64 * 128];
    const int tid = threadIdx.x;
    const int row0 = blockIdx.x * 64;
    #pragma unroll
    for (int it = 0; it < 8; ++it) {
        int idx4 = it * 256 + tid;
        int r = idx4 >> 5;
        int c = (idx4 & 31) * 4;
        float4 v = {0.f, 0.f, 0.f, 0.f};
        if (row0 + r < NN) v = *(const float4*)(x + (size_t)(row0 + r) * 128 + c);
        short4 sw; sw.x = f2bf(v.x); sw.y = f2bf(v.y); sw.z = f2bf(v.z); sw.w = f2bf(v.w);
        int byte = (r * 256 + c * 2) ^ ((r & 7) << 4);
        *(short4*)((char*)xt + byte) = sw;
    }
    __syncthreads();
    const int lane = tid & 63, w = tid >> 6;
    const int l15 = lane & 15, lg = lane >> 4;
    const int rloc = w * 16 + l15;
    s16x8 a[4];
    #pragma unroll
    for (int ks = 0; ks < 4; ++ks) {
        int byte = (rloc * 256 + (ks * 32 + lg * 8) * 2) ^ ((rloc & 7) << 4);
        a[ks] = *(const s16x8*)((const char*)xt + byte);
    }
    const int rowC = row0 + w * 16 + lg * 4;
    for (int nc = 0; nc < 18; ++nc) {
        f32x4 acc[4];
        s16x8 b[16];
        #pragma unroll
        for (int q = 0; q < 4; ++q) {
            acc[q] = (f32x4){0.f, 0.f, 0.f, 0.f};
            int j = (nc * 4 + q) * 16 + l15;
            #pragma unroll
            for (int ks = 0; ks < 4; ++ks)
                b[q * 4 + ks] = *(const s16x8*)(nodeW_t + j * 128 + ks * 32 + lg * 8);
        }
        #pragma unroll
        for (int q = 0; q < 4; ++q)
            #pragma unroll
            for (int ks = 0; ks < 4; ++ks)
                acc[q] = mfma16(a[ks], b[q * 4 + ks], acc[q]);
        #pragma unroll
        for (int q = 0; q < 4; ++q) {
            int j = (nc * 4 + q) * 16 + l15;
            #pragma unroll
            for (int r = 0; r < 4; ++r) {
                int row = rowC + r;
                if (row >= NN) continue;
                if (j < 512)       Kv_all[(size_t)row * 512 + j] = f2bf(acc[q][r]);
                else if (j < 1024) Vv_all[(size_t)row * 512 + (j - 512)] = f2bf(acc[q][r]);
                else               resid[(size_t)row * 128 + (j - 1024)] = acc[q][r];
            }
        }
    }
}

// ---------------- fused edge pipeline: 32 edges/block, col-split waves ----------------
// LDS map (50176 B):
//   EFT  @0     [32][128]bf16 8K   persistent (staged once)
//   Q    @8192  8K  [gather->B]  / VV overlay (written P3, read stage C)
//   K1   @16384 8K  [gather->B]  \ GATE @16384 [32][256] 16K (B-end -> C-epi)
//   KE   @24576 8K  [A->B]       /  M2 @16384 [32][128] 8K (D-epi -> E)
//   VE   @32768 8K  [A->C]       \ M1G @32768 [32][256] 16K (C-epi -> D)
//   PART @49152 1K  [D partials]
#define EFT_O  0
#define Q_O    8192
#define VV_O   8192
#define K1_O   16384
#define GATE_O 16384
#define M2_O   16384
#define KE_O   24576
#define VE_O   32768
#define M1G_O  32768
#define PART_O 49152

__global__ __launch_bounds__(256, 3)
void edge_kernel(const float* __restrict__ ef, const int* __restrict__ eidx,
                 const short* __restrict__ Kv_all, const short* __restrict__ Vv_all,
                 const short* __restrict__ KW_t, const short* __restrict__ VW_t,
                 const short* __restrict__ luW_t, const short* __restrict__ msgW_t,
                 const short* __restrict__ catW_t,
                 const float* __restrict__ lu_b, const float* __restrict__ ln1_g,
                 const float* __restrict__ ln1_b, const float* __restrict__ msg_b,
                 const float* __restrict__ ln2_g, const float* __restrict__ ln2_b,
                 float* __restrict__ out1)
{
    __shared__ alignas(16) char lds[50176];
    const int tid = threadIdx.x;
    const int lane = tid & 63, w = tid >> 6;
    const int l15 = lane & 15, lg = lane >> 4;
    const int e0b = blockIdx.x * 32;
    const float scale = 0.0625f;   // 1/sqrt(2*OUT)

    // gather assignment: 8 lanes per edge row (8 edges per wave), 16 cols each
    const int gRow = lane >> 3;            // 0..7
    const int gChunk = lane & 7;           // 0..7
    const int srcG = eidx[e0b + w * 8 + gRow];
    const int dstG = eidx[NE + e0b + w * 8 + gRow];
    int dstE[2][4];
    #pragma unroll
    for (int rt = 0; rt < 2; ++rt)
        #pragma unroll
        for (int r = 0; r < 4; ++r)
            dstE[rt][r] = eidx[NE + e0b + rt * 16 + lg * 4 + r];

    // prologue: q/k1 gather (head 0) + eft staging
    s16x8 qg[2], kg[2];
    #pragma unroll
    for (int j = 0; j < 2; ++j) {
        qg[j] = *(const s16x8*)(Kv_all + (size_t)dstG * 512 + gChunk * 16 + j * 8);
        kg[j] = *(const s16x8*)(Kv_all + (size_t)srcG * 512 + gChunk * 16 + j * 8);
    }
    #pragma unroll
    for (int it = 0; it < 4; ++it) {
        int idx = it * 256 + tid;
        int r = idx >> 5;
        int c4 = idx & 31;                 // col = c4*4
        float4 v = *(const float4*)(ef + (size_t)(e0b + r) * 128 + c4 * 4);
        short4 sw; sw.x = f2bf(v.x); sw.y = f2bf(v.y); sw.z = f2bf(v.z); sw.w = f2bf(v.w);
        int byte = (r * 256 + c4 * 8) ^ ((r & 7) << 4);
        *(short4*)(lds + EFT_O + byte) = sw;
    }
    {
        const int row = w * 8 + gRow;
        #pragma unroll
        for (int j = 0; j < 2; ++j) {
            const int byte = (row * 256 + (gChunk * 16 + j * 8) * 2) ^ ((row & 7) << 4);
            *(s16x8*)(lds + Q_O + byte) = qg[j];
            *(s16x8*)(lds + K1_O + byte) = kg[j];
        }
    }
    __syncthreads();   // B1

    f32x4 outc[2][2];
    #pragma unroll
    for (int ct = 0; ct < 2; ++ct)
        #pragma unroll
        for (int rt = 0; rt < 2; ++rt) outc[ct][rt] = (f32x4){0.f, 0.f, 0.f, 0.f};

    for (int h = 0; h < HEADS; ++h) {
        // ---- P1: stage A (KE/VE col-split) + Vv gather issue ----
        s16x8 vg[2];
        #pragma unroll
        for (int j = 0; j < 2; ++j)
            vg[j] = *(const s16x8*)(Vv_all + (size_t)srcG * 512 + h * 128 + gChunk * 16 + j * 8);

        f32x4 aK[2][2], aV[2][2];
        #pragma unroll
        for (int ct = 0; ct < 2; ++ct)
            #pragma unroll
            for (int rt = 0; rt < 2; ++rt) { aK[ct][rt] = (f32x4){0,0,0,0}; aV[ct][rt] = (f32x4){0,0,0,0}; }
        #pragma unroll
        for (int ks = 0; ks < 4; ++ks) {
            const int ac = (ks * 32 + lg * 8) * 2;
            const int sw = (l15 & 7) << 4;
            s16x8 a0 = *(const s16x8*)(lds + EFT_O + ((l15 * 256 + ac) ^ sw));
            s16x8 a1 = *(const s16x8*)(lds + EFT_O + (((16 + l15) * 256 + ac) ^ sw));
            const short* bK = KW_t + (size_t)(h * 128 + w * 32 + l15) * 128 + ks * 32 + lg * 8;
            const short* bV = VW_t + (size_t)(h * 128 + w * 32 + l15) * 128 + ks * 32 + lg * 8;
            s16x8 bk0 = *(const s16x8*)(bK);
            s16x8 bk1 = *(const s16x8*)(bK + 2048);
            s16x8 bv0 = *(const s16x8*)(bV);
            s16x8 bv1 = *(const s16x8*)(bV + 2048);
            aK[0][0] = mfma16(a0, bk0, aK[0][0]); aK[0][1] = mfma16(a1, bk0, aK[0][1]);
            aK[1][0] = mfma16(a0, bk1, aK[1][0]); aK[1][1] = mfma16(a1, bk1, aK[1][1]);
            aV[0][0] = mfma16(a0, bv0, aV[0][0]); aV[0][1] = mfma16(a1, bv0, aV[0][1]);
            aV[1][0] = mfma16(a0, bv1, aV[1][0]); aV[1][1] = mfma16(a1, bv1, aV[1][1]);
        }
        #pragma unroll
        for (int ct = 0; ct < 2; ++ct) {
            const int col = w * 32 + ct * 16 + l15;
            #pragma unroll
            for (int rt = 0; rt < 2; ++rt)
                #pragma unroll
                for (int r = 0; r < 4; ++r) {
                    const int row = rt * 16 + lg * 4 + r;
                    const int byte = (row * 256 + col * 2) ^ ((row & 7) << 4);
                    *(short*)(lds + KE_O + byte) = f2bf(aK[ct][rt][r]);
                    *(short*)(lds + VE_O + byte) = f2bf(aV[ct][rt][r]);
                }
        }
        __syncthreads();   // B2

        // ---- P2: LN1 stats (row-split, in-wave) ----
        float al[2][16];
        float mean1[2], rstd1[2];
        #pragma unroll
        for (int r = 0; r < 2; ++r) {
            const int row = w * 8 + lg * 2 + r;
            const int sw = (row & 7) << 4;
            float s = 0.f, s2 = 0.f;
            #pragma unroll
            for (int nt = 0; nt < 8; ++nt) {
                const int off = (row * 256 + (nt * 16 + l15) * 2) ^ sw;
                float qv  = bf2f(*(const short*)(lds + Q_O + off));
                float k1v = bf2f(*(const short*)(lds + K1_O + off));
                float kev = bf2f(*(const short*)(lds + KE_O + off));
                float alo = qv * k1v * scale;
                float ahi = qv * kev * scale;
                al[r][nt] = alo; al[r][nt + 8] = ahi;
                s += alo + ahi; s2 += alo * alo + ahi * ahi;
            }
            #pragma unroll
            for (int m = 1; m < 16; m <<= 1) { s += __shfl_xor(s, m); s2 += __shfl_xor(s2, m); }
            mean1[r] = s * (1.f / 256.f);
            float var = s2 * (1.f / 256.f) - mean1[r] * mean1[r];
            rstd1[r] = rsqrtf(var + EPSV);
        }
        __syncthreads();   // B3  (all Q/K1/KE reads done)

        // ---- P3: write gate + Vv ----
        #pragma unroll
        for (int r = 0; r < 2; ++r) {
            const int row = w * 8 + lg * 2 + r;
            const int sw = (row & 7) << 4;
            #pragma unroll
            for (int i2 = 0; i2 < 16; ++i2) {
                const int col = i2 * 16 + l15;
                float z = (al[r][i2] - mean1[r]) * rstd1[r] * ln1_g[h * 256 + col] + ln1_b[h * 256 + col];
                float g = 1.f / (1.f + __expf(-z));
                *(short*)(lds + GATE_O + ((row * 512 + col * 2) ^ sw)) = f2bf(g);
            }
        }
        {
            const int row = w * 8 + gRow;
            #pragma unroll
            for (int j = 0; j < 2; ++j) {
                const int byte = (row * 256 + (gChunk * 16 + j * 8) * 2) ^ ((row & 7) << 4);
                *(s16x8*)(lds + VV_O + byte) = vg[j];
            }
        }
        __syncthreads();   // B4

        // ---- P4: stage C MFMAs (col-split: 4 ct x 2 rt, B reused x2) ----
        f32x4 m1[4][2];
        #pragma unroll
        for (int ct = 0; ct < 4; ++ct)
            #pragma unroll
            for (int rt = 0; rt < 2; ++rt) m1[ct][rt] = (f32x4){0,0,0,0};
        #pragma unroll
        for (int ks = 0; ks < 8; ++ks) {
            const int sw = (l15 & 7) << 4;
            s16x8 a0, a1;
            if (ks < 4) {
                const int ac = (ks * 32 + lg * 8) * 2;
                a0 = *(const s16x8*)(lds + VV_O + ((l15 * 256 + ac) ^ sw));
                a1 = *(const s16x8*)(lds + VV_O + (((16 + l15) * 256 + ac) ^ sw));
            } else {
                const int ac = ((ks - 4) * 32 + lg * 8) * 2;
                a0 = *(const s16x8*)(lds + VE_O + ((l15 * 256 + ac) ^ sw));
                a1 = *(const s16x8*)(lds + VE_O + (((16 + l15) * 256 + ac) ^ sw));
            }
            const short* bp = luW_t + (size_t)(h * 256 + w * 64 + l15) * 256 + ks * 32 + lg * 8;
            s16x8 b0 = *(const s16x8*)(bp);
            s16x8 b1 = *(const s16x8*)(bp + 16 * 256);
            s16x8 b2 = *(const s16x8*)(bp + 32 * 256);
            s16x8 b3 = *(const s16x8*)(bp + 48 * 256);
            m1[0][0] = mfma16(a0, b0, m1[0][0]); m1[0][1] = mfma16(a1, b0, m1[0][1]);
            m1[1][0] = mfma16(a0, b1, m1[1][0]); m1[1][1] = mfma16(a1, b1, m1[1][1]);
            m1[2][0] = mfma16(a0, b2, m1[2][0]); m1[2][1] = mfma16(a1, b2, m1[2][1]);
            m1[3][0] = mfma16(a0, b3, m1[3][0]); m1[3][1] = mfma16(a1, b3, m1[3][1]);
        }
        __syncthreads();   // B5  (all VV/VE reads done)

        // ---- P5: stage C epilogue: gate * (m1+b) -> M1G ----
        #pragma unroll
        for (int ct = 0; ct < 4; ++ct) {
            const int col = w * 64 + ct * 16 + l15;
            const float lb = lu_b[h * 256 + col];
            #pragma unroll
            for (int rt = 0; rt < 2; ++rt)
                #pragma unroll
                for (int r = 0; r < 4; ++r) {
                    const int row = rt * 16 + lg * 4 + r;
                    const int sw = (row & 7) << 4;
                    float g = bf2f(*(const short*)(lds + GATE_O + ((row * 512 + col * 2) ^ sw)));
                    *(short*)(lds + M1G_O + ((row * 512 + col * 2) ^ sw)) =
                        f2bf((m1[ct][rt][r] + lb) * g);
                }
        }
        __syncthreads();   // B6

        // ---- P6: stage D MFMAs + LN2 partials ----
        f32x4 m2a[2][2];
        #pragma unroll
        for (int ct = 0; ct < 2; ++ct)
            #pragma unroll
            for (int rt = 0; rt < 2; ++rt) m2a[ct][rt] = (f32x4){0,0,0,0};
        #pragma unroll
        for (int ks = 0; ks < 8; ++ks) {
            const int ac = (ks * 32 + lg * 8) * 2;
            const int sw = (l15 & 7) << 4;
            s16x8 a0 = *(const s16x8*)(lds + M1G_O + ((l15 * 512 + ac) ^ sw));
            s16x8 a1 = *(const s16x8*)(lds + M1G_O + (((16 + l15) * 512 + ac) ^ sw));
            const short* bp = msgW_t + (size_t)(h * 128 + w * 32 + l15) * 256 + ks * 32 + lg * 8;
            s16x8 b0 = *(const s16x8*)(bp);
            s16x8 b1 = *(const s16x8*)(bp + 16 * 256);
            m2a[0][0] = mfma16(a0, b0, m2a[0][0]); m2a[0][1] = mfma16(a1, b0, m2a[0][1]);
            m2a[1][0] = mfma16(a0, b1, m2a[1][0]); m2a[1][1] = mfma16(a1, b1, m2a[1][1]);
        }
        {
            const float mb0 = msg_b[h * 128 + w * 32 + l15];
            const float mb1 = msg_b[h * 128 + w * 32 + 16 + l15];
            #pragma unroll
            for (int rt = 0; rt < 2; ++rt)
                #pragma unroll
                for (int r = 0; r < 4; ++r) {
                    float v0 = m2a[0][rt][r] + mb0;
                    float v1 = m2a[1][rt][r] + mb1;
                    m2a[0][rt][r] = v0; m2a[1][rt][r] = v1;
                    float s = v0 + v1, s2 = v0 * v0 + v1 * v1;
                    #pragma unroll
                    for (int m = 1; m < 16; m <<= 1) { s += __shfl_xor(s, m); s2 += __shfl_xor(s2, m); }
                    if (l15 == 0) {
                        const int row = rt * 16 + lg * 4 + r;
                        *(float2*)(lds + PART_O + row * 32 + w * 8) = make_float2(s, s2);
                    }
                }
        }
        __syncthreads();   // B7

        // ---- P7: finish LN2 + leaky -> M2; issue next-head q/k1 gather ----
        #pragma unroll
        for (int rt = 0; rt < 2; ++rt)
            #pragma unroll
            for (int r = 0; r < 4; ++r) {
                const int row = rt * 16 + lg * 4 + r;
                float4 pa = *(const float4*)(lds + PART_O + row * 32);
                float4 pb = *(const float4*)(lds + PART_O + row * 32 + 16);
                float s = pa.x + pa.z + pb.x + pb.z;
                float s2 = pa.y + pa.w + pb.y + pb.w;
                float mean = s * (1.f / 128.f);
                float var = s2 * (1.f / 128.f) - mean * mean;
                float rstd = rsqrtf(var + EPSV);
                #pragma unroll
                for (int ct = 0; ct < 2; ++ct) {
                    const int col = w * 32 + ct * 16 + l15;
                    float v = (m2a[ct][rt][r] - mean) * rstd * ln2_g[h * 128 + col] + ln2_b[h * 128 + col];
                    v = v > 0.f ? v : v * NEGS;
                    *(short*)(lds + M2_O + ((row * 256 + col * 2) ^ ((row & 7) << 4))) = f2bf(v);
                }
            }
        if (h < 3) {
            #pragma unroll
            for (int j = 0; j < 2; ++j) {
                qg[j] = *(const s16x8*)(Kv_all + (size_t)dstG * 512 + (h + 1) * 128 + gChunk * 16 + j * 8);
                kg[j] = *(const s16x8*)(Kv_all + (size_t)srcG * 512 + (h + 1) * 128 + gChunk * 16 + j * 8);
            }
        }
        __syncthreads();   // B8

        // ---- P8: stage E: outc += m2 @ catW_h ----
        #pragma unroll
        for (int ks = 0; ks < 4; ++ks) {
            const int ac = (ks * 32 + lg * 8) * 2;
            const int sw = (l15 & 7) << 4;
            s16x8 a0 = *(const s16x8*)(lds + M2_O + ((l15 * 256 + ac) ^ sw));
            s16x8 a1 = *(const s16x8*)(lds + M2_O + (((16 + l15) * 256 + ac) ^ sw));
            const short* bp = catW_t + (size_t)(h * 128 + w * 32 + l15) * 128 + ks * 32 + lg * 8;
            s16x8 b0 = *(const s16x8*)(bp);
            s16x8 b1 = *(const s16x8*)(bp + 16 * 128);
            outc[0][0] = mfma16(a0, b0, outc[0][0]); outc[0][1] = mfma16(a1, b0, outc[0][1]);
            outc[1][0] = mfma16(a0, b1, outc[1][0]); outc[1][1] = mfma16(a1, b1, outc[1][1]);
        }
        __syncthreads();   // B9  (M2 reads done before next head's K1 writes)

        // ---- P0 (next head): write q/k1 from prefetched regs ----
        if (h < 3) {
            const int row = w * 8 + gRow;
            #pragma unroll
            for (int j = 0; j < 2; ++j) {
                const int byte = (row * 256 + (gChunk * 16 + j * 8) * 2) ^ ((row & 7) << 4);
                *(s16x8*)(lds + Q_O + byte) = qg[j];
                *(s16x8*)(lds + K1_O + byte) = kg[j];
            }
        }
    }

    // ---- scatter: wave w owns cols w*32..w*32+32 for all 32 edges ----
    #pragma unroll
    for (int ct = 0; ct < 2; ++ct) {
        const int col = w * 32 + ct * 16 + l15;
        #pragma unroll
        for (int rt = 0; rt < 2; ++rt)
            #pragma unroll
            for (int r = 0; r < 4; ++r)
                atomicAdd(out1 + (size_t)dstE[rt][r] * 128 + col, outc[ct][rt][r]);
    }
}

// ---------------- BN statistics ----------------
__global__ void bn_stats(const float* __restrict__ out1, const float* __restrict__ cat_b,
                         float* __restrict__ stats)
{
    const int col = threadIdx.x;
    const int r0 = blockIdx.x * 128;
    const float cb = cat_b[col];
    float s = 0.f, s2 = 0.f;
    for (int i = 0; i < 128; ++i) {
        int row = r0 + i;
        if (row < NN) {
            float v = out1[(size_t)row * 128 + col] + cb;
            s += v; s2 += v * v;
        }
    }
    atomicAdd(stats + col, s);
    atomicAdd(stats + 128 + col, s2);
}

// ---------------- finalize: BN + leaky + residual ----------------
__global__ void finalize(const float* __restrict__ out1, const float* __restrict__ resid,
                         const float* __restrict__ stats, const float* __restrict__ cat_b,
                         const float* __restrict__ bn_g, const float* __restrict__ bn_b,
                         const float* __restrict__ inp_b, float* __restrict__ out)
{
    int i = blockIdx.x * 256 + threadIdx.x;
    if (i >= NN * 128) return;
    int col = i & 127;
    float mu = stats[col] * (1.f / NN);
    float var = stats[128 + col] * (1.f / NN) - mu * mu;
    float rstd = rsqrtf(var + EPSV);
    float v = out1[i] + cat_b[col];
    v = (v - mu) * rstd * bn_g[col] + bn_b[col];
    v = v > 0.f ? v : v * NEGS;
    out[i] = v + resid[i] + inp_b[col];
}

extern "C" void kernel_launch(void* const* d_in, const int* in_sizes, int n_in,
                              void* d_out, int out_size, void* d_ws, size_t ws_size,
                              hipStream_t stream)
{
    (void)in_sizes; (void)n_in; (void)out_size; (void)ws_size;
    const float* x     = (const float*)d_in[0];
    const int*   eidx  = (const int*)d_in[1];
    const float* ef    = (const float*)d_in[2];
    const float* Kv2v  = (const float*)d_in[3];
    const float* Ke2v  = (const float*)d_in[4];
    const float* Vv2v  = (const float*)d_in[5];
    const float* Ve2v  = (const float*)d_in[6];
    const float* lu_W  = (const float*)d_in[7];
    const float* lu_b  = (const float*)d_in[8];
    const float* ln1_g = (const float*)d_in[9];
    const float* ln1_b = (const float*)d_in[10];
    const float* msg_W = (const float*)d_in[11];
    const float* msg_b = (const float*)d_in[12];
    const float* ln2_g = (const float*)d_in[13];
    const float* ln2_b = (const float*)d_in[14];
    const float* cat_W = (const float*)d_in[15];
    const float* cat_b = (const float*)d_in[16];
    const float* inp_W = (const float*)d_in[17];
    const float* inp_b = (const float*)d_in[18];
    const float* bn_g  = (const float*)d_in[19];
    const float* bn_b  = (const float*)d_in[20];

    char* ws = (char*)d_ws;
    short* nodeW_t = (short*)(ws + 0);          // 294912
    short* KW_t    = (short*)(ws + 294912);     // 131072
    short* VW_t    = (short*)(ws + 425984);     // 131072
    short* luW_t   = (short*)(ws + 557056);     // 524288
    short* msgW_t  = (short*)(ws + 1081344);    // 262144
    short* catW_t  = (short*)(ws + 1343488);    // 131072
    short* Kv_all  = (short*)(ws + 1474560);    // 51,200,000
    short* Vv_all  = (short*)(ws + 52674560);   // 51,200,000
    float* resid   = (float*)(ws + 103874560);  // 25,600,000
    float* out1    = (float*)(ws + 129474560);  // 25,600,000
    float* stats   = (float*)(ws + 155074560);  // 1024

    hipMemsetAsync(out1, 0, 25600000 + 1024, stream);   // out1 + stats (contiguous)
    prep_weights<<<2880, 256, 0, stream>>>(Kv2v, Vv2v, inp_W, Ke2v, Ve2v, lu_W, msg_W, cat_W,
                                           nodeW_t, KW_t, VW_t, luW_t, msgW_t, catW_t);
    node_proj<<<782, 256, 0, stream>>>(x, nodeW_t, Kv_all, Vv_all, resid);
    edge_kernel<<<6250, 256, 0, stream>>>(ef, eidx, Kv_all, Vv_all, KW_t, VW_t, luW_t,
                                          msgW_t, catW_t, lu_b, ln1_g, ln1_b, msg_b,
                                          ln2_g, ln2_b, out1);
    bn_stats<<<391, 128, 0, stream>>>(out1, cat_b, stats);
    finalize<<<25000, 256, 0, stream>>>(out1, resid, stats, cat_b, bn_g, bn_b, inp_b,
                                        (float*)d_out);
}

// Round 6
// 1972.482 us; speedup vs baseline: 1.8598x; 1.2320x over previous
//
#include <hip/hip_runtime.h>
#include <hip/hip_bf16.h>

#define NN 50000
#define NE 200000
#define HEADS 4
#define EPSV 1e-5f
#define NEGS 0.01f

using f32x4 = __attribute__((ext_vector_type(4))) float;
using s16x8 = __attribute__((ext_vector_type(8))) short;
using bf16x8 = __attribute__((ext_vector_type(8))) __bf16;

__device__ __forceinline__ short f2bf(float f) {
    union { float f; unsigned u; } v; v.f = f;
    unsigned r = v.u + 0x7FFFu + ((v.u >> 16) & 1u);
    return (short)(r >> 16);
}
__device__ __forceinline__ float bf2f(short s) {
    union { unsigned u; float f; } v; v.u = ((unsigned)(unsigned short)s) << 16;
    return v.f;
}
__device__ __forceinline__ f32x4 mfma16(s16x8 a, s16x8 b, f32x4 c) {
    return __builtin_amdgcn_mfma_f32_16x16x32_bf16(
        __builtin_bit_cast(bf16x8, a), __builtin_bit_cast(bf16x8, b), c, 0, 0, 0);
}
__device__ __forceinline__ void gld16(const void* g, void* l) {
    __builtin_amdgcn_global_load_lds(
        (const __attribute__((address_space(1))) void*)g,
        (__attribute__((address_space(3))) void*)l, 16, 0, 0);
}
// DMA one 32KB chunk (16384 shorts) image -> LDS, all 256 threads
__device__ __forceinline__ void dma_chunk(const short* src, char* dst, int w, int lane) {
    #pragma unroll
    for (int op = 0; op < 8; ++op)
        gld16(src + op * 2048 + w * 512 + lane * 8, dst + op * 4096 + w * 1024);
}

// ---------------- weight prep ----------------
// nodeW_t: [1152][128] plain transposed (for node_proj)
// imgW: per-head 294912B pre-swizzled LDS images:
//   KW @0 (16384 sh), VW @16384, LU c0..c3 @32768+c*16384, MSG c0,c1 @98304+c*16384, CAT @131072
//   image entry (colc,k): idx = (colc*K + k) ^ ((colc&7)<<3)   [shorts]
__global__ void prep_weights(const float* __restrict__ Kv2v, const float* __restrict__ Vv2v,
                             const float* __restrict__ inpW,
                             const float* __restrict__ Ke2v, const float* __restrict__ Ve2v,
                             const float* __restrict__ luW, const float* __restrict__ msgW,
                             const float* __restrict__ catW,
                             short* __restrict__ nodeW_t, short* __restrict__ imgW)
{
    int i = blockIdx.x * 256 + threadIdx.x;
    if (i < 147456) {                       // nodeW_t [1152][128]
        int j = i >> 7, k = i & 127;
        float v;
        if (j < 512)       v = Kv2v[(j >> 7) * 16384 + k * 128 + (j & 127)];
        else if (j < 1024) v = Vv2v[((j - 512) >> 7) * 16384 + k * 128 + (j & 127)];
        else               v = inpW[k * 128 + (j - 1024)];
        nodeW_t[i] = f2bf(v);
        return;
    }
    i -= 147456;
    if (i >= 589824) return;
    int h = i / 147456;
    int r = i % 147456;
    short* img = imgW + h * 147456;
    if (r < 16384) {                        // KW (K=128)
        int colc = r >> 7, k = r & 127;
        img[(colc * 128 + k) ^ ((colc & 7) << 3)] = f2bf(Ke2v[h * 16384 + k * 128 + colc]);
    } else if (r < 32768) {                 // VW (K=128)
        int e = r - 16384; int colc = e >> 7, k = e & 127;
        img[16384 + ((colc * 128 + k) ^ ((colc & 7) << 3))] = f2bf(Ve2v[h * 16384 + k * 128 + colc]);
    } else if (r < 98304) {                 // LU (K=256, 4 chunks of 64 cols)
        int e = r - 32768; int c = e >> 14, ec = e & 16383;
        int colc = ec >> 8, k = ec & 255; int col = c * 64 + colc;
        img[32768 + c * 16384 + ((colc * 256 + k) ^ ((colc & 7) << 3))] =
            f2bf(luW[h * 65536 + k * 256 + col]);
    } else if (r < 131072) {                // MSG (K=256, 2 chunks of 64 cols)
        int e = r - 98304; int c = e >> 14, ec = e & 16383;
        int colc = ec >> 8, k = ec & 255; int col = c * 64 + colc;
        img[98304 + c * 16384 + ((colc * 256 + k) ^ ((colc & 7) << 3))] =
            f2bf(msgW[h * 32768 + k * 128 + col]);
    } else {                                // CAT (K=128)
        int e = r - 131072; int colc = e >> 7, k = e & 127;
        img[131072 + ((colc * 128 + k) ^ ((colc & 7) << 3))] =
            f2bf(catW[(h * 128 + k) * 128 + colc]);
    }
}

// ---------------- node projections (unchanged, verified) ----------------
__global__ __launch_bounds__(256, 2)
void node_proj(const float* __restrict__ x, const short* __restrict__ nodeW_t,
               short* __restrict__ Kv_all, short* __restrict__ Vv_all,
               float* __restrict__ resid)
{
    __shared__ alignas(16) short xt[64 * 128];
    const int tid = threadIdx.x;
    const int row0 = blockIdx.x * 64;
    #pragma unroll
    for (int it = 0; it < 8; ++it) {
        int idx4 = it * 256 + tid;
        int r = idx4 >> 5;
        int c = (idx4 & 31) * 4;
        float4 v = {0.f, 0.f, 0.f, 0.f};
        if (row0 + r < NN) v = *(const float4*)(x + (size_t)(row0 + r) * 128 + c);
        short4 sw; sw.x = f2bf(v.x); sw.y = f2bf(v.y); sw.z = f2bf(v.z); sw.w = f2bf(v.w);
        int byte = (r * 256 + c * 2) ^ ((r & 7) << 4);
        *(short4*)((char*)xt + byte) = sw;
    }
    __syncthreads();
    const int lane = tid & 63, w = tid >> 6;
    const int l15 = lane & 15, lg = lane >> 4;
    const int rloc = w * 16 + l15;
    s16x8 a[4];
    #pragma unroll
    for (int ks = 0; ks < 4; ++ks) {
        int byte = (rloc * 256 + (ks * 32 + lg * 8) * 2) ^ ((rloc & 7) << 4);
        a[ks] = *(const s16x8*)((const char*)xt + byte);
    }
    const int rowC = row0 + w * 16 + lg * 4;
    for (int nc = 0; nc < 18; ++nc) {
        f32x4 acc[4];
        s16x8 b[16];
        #pragma unroll
        for (int q = 0; q < 4; ++q) {
            acc[q] = (f32x4){0.f, 0.f, 0.f, 0.f};
            int j = (nc * 4 + q) * 16 + l15;
            #pragma unroll
            for (int ks = 0; ks < 4; ++ks)
                b[q * 4 + ks] = *(const s16x8*)(nodeW_t + j * 128 + ks * 32 + lg * 8);
        }
        #pragma unroll
        for (int q = 0; q < 4; ++q)
            #pragma unroll
            for (int ks = 0; ks < 4; ++ks)
                acc[q] = mfma16(a[ks], b[q * 4 + ks], acc[q]);
        #pragma unroll
        for (int q = 0; q < 4; ++q) {
            int j = (nc * 4 + q) * 16 + l15;
            #pragma unroll
            for (int r = 0; r < 4; ++r) {
                int row = rowC + r;
                if (row >= NN) continue;
                if (j < 512)       Kv_all[(size_t)row * 512 + j] = f2bf(acc[q][r]);
                else if (j < 1024) Vv_all[(size_t)row * 512 + (j - 512)] = f2bf(acc[q][r]);
                else               resid[(size_t)row * 128 + (j - 1024)] = acc[q][r];
            }
        }
    }
}

// ---------------- fused edge pipeline: LDS-staged weights, dbuf DMA ----------------
// dynamic LDS 114688: wbuf0 @0 (32K), wbuf1 @32768 (32K), per-wave scratch @65536 + w*12288:
//   q@0 [16][128], k1@4096, VE/m2@8192 [16][128], m1g@0 [16][256] (overlays q/k1)
#define B128(buf, ct, ks) \
    (*(const s16x8*)((const short*)(buf) + (((((ct) * 16 + l15) * 128) + (ks) * 32 + lg * 8) ^ ((l15 & 7) << 3))))
#define B256(buf, ct, ks) \
    (*(const s16x8*)((const short*)(buf) + (((((ct) * 16 + l15) * 256) + (ks) * 32 + lg * 8) ^ ((l15 & 7) << 3))))
#define CB() do { __syncthreads(); char* _t = bA; bA = bB; bB = _t; } while (0)

__global__ __launch_bounds__(256, 1)
void edge_kernel(const float* __restrict__ ef, const int* __restrict__ eidx,
                 const short* __restrict__ Kv_all, const short* __restrict__ Vv_all,
                 const short* __restrict__ imgW,
                 const float* __restrict__ lu_b, const float* __restrict__ ln1_g,
                 const float* __restrict__ ln1_b, const float* __restrict__ msg_b,
                 const float* __restrict__ ln2_g, const float* __restrict__ ln2_b,
                 float* __restrict__ out1)
{
    extern __shared__ char lds[];
    char* bA = lds;
    char* bB = lds + 32768;
    const int tid = threadIdx.x;
    const int lane = tid & 63, w = tid >> 6;
    const int l15 = lane & 15, lg = lane >> 4;
    const int e0 = blockIdx.x * 64 + w * 16;
    const int rb = lg * 4;
    char* myscr = lds + 65536 + w * 12288;
    const float scale = 0.0625f;   // 1/sqrt(2*OUT)

    // prologue: DMA KW(h=0) into bB; ef A-fragments; indices
    dma_chunk(imgW, bB, w, lane);
    const float* efr = ef + (size_t)(e0 + l15) * 128 + lg * 8;
    s16x8 aef[4];
    #pragma unroll
    for (int ks = 0; ks < 4; ++ks) {
        float4 v0 = *(const float4*)(efr + ks * 32);
        float4 v1 = *(const float4*)(efr + ks * 32 + 4);
        s16x8 t;
        t[0] = f2bf(v0.x); t[1] = f2bf(v0.y); t[2] = f2bf(v0.z); t[3] = f2bf(v0.w);
        t[4] = f2bf(v1.x); t[5] = f2bf(v1.y); t[6] = f2bf(v1.z); t[7] = f2bf(v1.w);
        aef[ks] = t;
    }
    const int srcA = eidx[e0 + l15];
    int dstC[4];
    #pragma unroll
    for (int r = 0; r < 4; ++r) dstC[r] = eidx[NE + e0 + rb + r];
    const int gRow = lane >> 2;            // 0..15
    const int gChunk = lane & 3;           // 0..3
    const int dstG = eidx[NE + e0 + gRow];
    const int srcG = eidx[e0 + gRow];

    f32x4 outc[8];
    #pragma unroll
    for (int nt = 0; nt < 8; ++nt) outc[nt] = (f32x4){0.f, 0.f, 0.f, 0.f};
    CB();   // KW0 ready in bA

    for (int h = 0; h < HEADS; ++h) {
        const short* hb = imgW + h * 147456;
        // q/k1 gathers (latency hidden under step 1)
        s16x8 qv[4], kv[4];
        #pragma unroll
        for (int j = 0; j < 4; ++j) {
            qv[j] = *(const s16x8*)(Kv_all + (size_t)dstG * 512 + h * 128 + gChunk * 32 + j * 8);
            kv[j] = *(const s16x8*)(Kv_all + (size_t)srcG * 512 + h * 128 + gChunk * 32 + j * 8);
        }

        // ---- step 1: DMA VW; accK = ef@KW (bA) ----
        dma_chunk(hb + 16384, bB, w, lane);
        f32x4 accK[8];
        #pragma unroll
        for (int nt = 0; nt < 8; ++nt) accK[nt] = (f32x4){0, 0, 0, 0};
        #pragma unroll
        for (int ks = 0; ks < 4; ++ks)
            #pragma unroll
            for (int ct = 0; ct < 8; ++ct)
                accK[ct] = mfma16(aef[ks], B128(bA, ct, ks), accK[ct]);
        #pragma unroll
        for (int j = 0; j < 4; ++j) {       // q/k1 -> scratch
            int byte = gRow * 256 + ((((gChunk * 4 + j) * 16)) ^ ((gRow & 7) << 4));
            *(s16x8*)(myscr + byte) = qv[j];
            *(s16x8*)(myscr + 4096 + byte) = kv[j];
        }
        CB();

        // ---- step 2: DMA LU0; accV = ef@VW (bA); VE->scratch; LN1+gate; vvr ----
        dma_chunk(hb + 32768, bB, w, lane);
        f32x4 accV[8];
        #pragma unroll
        for (int nt = 0; nt < 8; ++nt) accV[nt] = (f32x4){0, 0, 0, 0};
        #pragma unroll
        for (int ks = 0; ks < 4; ++ks)
            #pragma unroll
            for (int ct = 0; ct < 8; ++ct)
                accV[ct] = mfma16(aef[ks], B128(bA, ct, ks), accV[ct]);
        #pragma unroll
        for (int nt = 0; nt < 8; ++nt) {    // VE -> scratch @8192 [16][128]
            int c = nt * 16 + l15;
            #pragma unroll
            for (int r = 0; r < 4; ++r) {
                int row = rb + r;
                int byte = 8192 + ((row * 256 + c * 2) ^ ((row & 7) << 4));
                *(short*)(myscr + byte) = f2bf(accV[nt][r]);
            }
        }
        s16x8 vvr[4];
        #pragma unroll
        for (int ks = 0; ks < 4; ++ks)
            vvr[ks] = *(const s16x8*)(Vv_all + (size_t)srcA * 512 + h * 128 + ks * 32 + lg * 8);
        unsigned gpk[16][2];
        #pragma unroll
        for (int r = 0; r < 4; ++r) {       // LN1 + sigmoid gate (R4-verified)
            const int i = rb + r;
            const int swz = (i & 7) << 4;
            float al[16];
            float s = 0.f, s2 = 0.f;
            #pragma unroll
            for (int nt = 0; nt < 8; ++nt) {
                int off = (i * 256 + nt * 32 + l15 * 2) ^ swz;
                float q  = bf2f(*(const short*)(myscr + off));
                float k1 = bf2f(*(const short*)(myscr + 4096 + off));
                float alo = q * k1 * scale;
                float ahi = q * accK[nt][r] * scale;
                al[nt] = alo; al[nt + 8] = ahi;
                s += alo + ahi; s2 += alo * alo + ahi * ahi;
            }
            #pragma unroll
            for (int m = 1; m < 16; m <<= 1) { s += __shfl_xor(s, m); s2 += __shfl_xor(s2, m); }
            float mean = s * (1.f / 256.f);
            float var  = s2 * (1.f / 256.f) - mean * mean;
            float rstd = rsqrtf(var + EPSV);
            #pragma unroll
            for (int i2 = 0; i2 < 16; ++i2) {
                int c = i2 * 16 + l15;
                float z = (al[i2] - mean) * rstd * ln1_g[h * 256 + c] + ln1_b[h * 256 + c];
                float g = 1.f / (1.f + __expf(-z));
                unsigned gb = (unsigned)(unsigned short)f2bf(g);
                if ((r & 1) == 0) gpk[i2][r >> 1] = gb;
                else              gpk[i2][r >> 1] |= gb << 16;
            }
        }
        CB();

        // ---- steps 3-6: stage C, luW chunks c=0..3 (64 cols each) ----
        f32x4 m1[16];
        #pragma unroll
        for (int nt = 0; nt < 16; ++nt) m1[nt] = (f32x4){0, 0, 0, 0};
        #pragma unroll
        for (int c = 0; c < 4; ++c) {
            dma_chunk(c < 3 ? hb + 32768 + (c + 1) * 16384 : hb + 98304, bB, w, lane);
            #pragma unroll
            for (int ks = 0; ks < 8; ++ks) {
                s16x8 a;
                if (ks < 4) a = vvr[ks];
                else {
                    int byte = 8192 + ((l15 * 256 + ((ks - 4) * 32 + lg * 8) * 2) ^ ((l15 & 7) << 4));
                    a = *(const s16x8*)(myscr + byte);
                }
                #pragma unroll
                for (int ct = 0; ct < 4; ++ct)
                    m1[c * 4 + ct] = mfma16(a, B256(bA, ct, ks), m1[c * 4 + ct]);
            }
            CB();
        }
        #pragma unroll
        for (int nt = 0; nt < 16; ++nt) {   // m1g -> scratch @0 [16][256] (overlays q/k1)
            int c = nt * 16 + l15;
            float bias = lu_b[h * 256 + c];
            #pragma unroll
            for (int r = 0; r < 4; ++r) {
                float g = bf2f((short)((gpk[nt][r >> 1] >> ((r & 1) * 16)) & 0xFFFFu));
                int row = rb + r;
                int byte = (row * 512 + c * 2) ^ ((row & 7) << 4);
                *(short*)(myscr + byte) = f2bf((m1[nt][r] + bias) * g);
            }
        }

        // ---- steps 7-8: stage D, msgW chunks c=0..1 ----
        f32x4 m2[8];
        #pragma unroll
        for (int nt = 0; nt < 8; ++nt) m2[nt] = (f32x4){0, 0, 0, 0};
        #pragma unroll
        for (int c = 0; c < 2; ++c) {
            dma_chunk(c == 0 ? hb + 114688 : hb + 131072, bB, w, lane);
            #pragma unroll
            for (int ks = 0; ks < 8; ++ks) {
                int byte = (l15 * 512 + (ks * 32 + lg * 8) * 2) ^ ((l15 & 7) << 4);
                s16x8 a = *(const s16x8*)(myscr + byte);
                #pragma unroll
                for (int ct = 0; ct < 4; ++ct)
                    m2[c * 4 + ct] = mfma16(a, B256(bA, ct, ks), m2[c * 4 + ct]);
            }
            CB();
        }
        {   // LN2 + leaky -> m2 scratch @8192 (R4-verified)
            float s[4] = {0, 0, 0, 0}, s2[4] = {0, 0, 0, 0};
            #pragma unroll
            for (int nt = 0; nt < 8; ++nt) {
                int c = nt * 16 + l15;
                float bias = msg_b[h * 128 + c];
                #pragma unroll
                for (int r = 0; r < 4; ++r) {
                    float v = m2[nt][r] + bias;
                    m2[nt][r] = v;
                    s[r] += v; s2[r] += v * v;
                }
            }
            #pragma unroll
            for (int m = 1; m < 16; m <<= 1)
                #pragma unroll
                for (int r = 0; r < 4; ++r) { s[r] += __shfl_xor(s[r], m); s2[r] += __shfl_xor(s2[r], m); }
            float mean[4], rstd[4];
            #pragma unroll
            for (int r = 0; r < 4; ++r) {
                mean[r] = s[r] * (1.f / 128.f);
                float var = s2[r] * (1.f / 128.f) - mean[r] * mean[r];
                rstd[r] = rsqrtf(var + EPSV);
            }
            #pragma unroll
            for (int nt = 0; nt < 8; ++nt) {
                int c = nt * 16 + l15;
                float g2 = ln2_g[h * 128 + c], b2 = ln2_b[h * 128 + c];
                #pragma unroll
                for (int r = 0; r < 4; ++r) {
                    float v = (m2[nt][r] - mean[r]) * rstd[r] * g2 + b2;
                    v = v > 0.f ? v : v * NEGS;
                    int row = rb + r;
                    int byte = 8192 + ((row * 256 + c * 2) ^ ((row & 7) << 4));
                    *(short*)(myscr + byte) = f2bf(v);
                }
            }
        }

        // ---- step 9: DMA KW(h+1); stage E from bA (CAT) ----
        if (h < 3) dma_chunk(imgW + (h + 1) * 147456, bB, w, lane);
        #pragma unroll
        for (int ks = 0; ks < 4; ++ks) {
            int byte = 8192 + ((l15 * 256 + (ks * 32 + lg * 8) * 2) ^ ((l15 & 7) << 4));
            s16x8 a = *(const s16x8*)(myscr + byte);
            #pragma unroll
            for (int ct = 0; ct < 8; ++ct)
                outc[ct] = mfma16(a, B128(bA, ct, ks), outc[ct]);
        }
        CB();
    }

    // ---- scatter: one 128-wide atomic add per edge ----
    #pragma unroll
    for (int nt = 0; nt < 8; ++nt) {
        int c = nt * 16 + l15;
        #pragma unroll
        for (int r = 0; r < 4; ++r)
            atomicAdd(out1 + (size_t)dstC[r] * 128 + c, outc[nt][r]);
    }
}

// ---------------- BN statistics ----------------
__global__ void bn_stats(const float* __restrict__ out1, const float* __restrict__ cat_b,
                         float* __restrict__ stats)
{
    const int col = threadIdx.x;
    const int r0 = blockIdx.x * 128;
    const float cb = cat_b[col];
    float s = 0.f, s2 = 0.f;
    for (int i = 0; i < 128; ++i) {
        int row = r0 + i;
        if (row < NN) {
            float v = out1[(size_t)row * 128 + col] + cb;
            s += v; s2 += v * v;
        }
    }
    atomicAdd(stats + col, s);
    atomicAdd(stats + 128 + col, s2);
}

// ---------------- finalize: BN + leaky + residual ----------------
__global__ void finalize(const float* __restrict__ out1, const float* __restrict__ resid,
                         const float* __restrict__ stats, const float* __restrict__ cat_b,
                         const float* __restrict__ bn_g, const float* __restrict__ bn_b,
                         const float* __restrict__ inp_b, float* __restrict__ out)
{
    int i = blockIdx.x * 256 + threadIdx.x;
    if (i >= NN * 128) return;
    int col = i & 127;
    float mu = stats[col] * (1.f / NN);
    float var = stats[128 + col] * (1.f / NN) - mu * mu;
    float rstd = rsqrtf(var + EPSV);
    float v = out1[i] + cat_b[col];
    v = (v - mu) * rstd * bn_g[col] + bn_b[col];
    v = v > 0.f ? v : v * NEGS;
    out[i] = v + resid[i] + inp_b[col];
}

extern "C" void kernel_launch(void* const* d_in, const int* in_sizes, int n_in,
                              void* d_out, int out_size, void* d_ws, size_t ws_size,
                              hipStream_t stream)
{
    (void)in_sizes; (void)n_in; (void)out_size; (void)ws_size;
    const float* x     = (const float*)d_in[0];
    const int*   eidx  = (const int*)d_in[1];
    const float* ef    = (const float*)d_in[2];
    const float* Kv2v  = (const float*)d_in[3];
    const float* Ke2v  = (const float*)d_in[4];
    const float* Vv2v  = (const float*)d_in[5];
    const float* Ve2v  = (const float*)d_in[6];
    const float* lu_W  = (const float*)d_in[7];
    const float* lu_b  = (const float*)d_in[8];
    const float* ln1_g = (const float*)d_in[9];
    const float* ln1_b = (const float*)d_in[10];
    const float* msg_W = (const float*)d_in[11];
    const float* msg_b = (const float*)d_in[12];
    const float* ln2_g = (const float*)d_in[13];
    const float* ln2_b = (const float*)d_in[14];
    const float* cat_W = (const float*)d_in[15];
    const float* cat_b = (const float*)d_in[16];
    const float* inp_W = (const float*)d_in[17];
    const float* inp_b = (const float*)d_in[18];
    const float* bn_g  = (const float*)d_in[19];
    const float* bn_b  = (const float*)d_in[20];

    char* ws = (char*)d_ws;
    short* nodeW_t = (short*)(ws + 0);          // 294912
    short* imgW    = (short*)(ws + 294912);     // 1179648 (4 heads x 294912)
    short* Kv_all  = (short*)(ws + 1474560);    // 51,200,000
    short* Vv_all  = (short*)(ws + 52674560);   // 51,200,000
    float* resid   = (float*)(ws + 103874560);  // 25,600,000
    float* out1    = (float*)(ws + 129474560);  // 25,600,000
    float* stats   = (float*)(ws + 155074560);  // 1024

    static int attr_set = 0;   // idempotent config, not state-dependent work
    hipFuncSetAttribute((const void*)edge_kernel,
                        hipFuncAttributeMaxDynamicSharedMemorySize, 114688);

    hipMemsetAsync(out1, 0, 25600000 + 1024, stream);   // out1 + stats (contiguous)
    prep_weights<<<2880, 256, 0, stream>>>(Kv2v, Vv2v, inp_W, Ke2v, Ve2v, lu_W, msg_W, cat_W,
                                           nodeW_t, imgW);
    node_proj<<<782, 256, 0, stream>>>(x, nodeW_t, Kv_all, Vv_all, resid);
    edge_kernel<<<3125, 256, 114688, stream>>>(ef, eidx, Kv_all, Vv_all, imgW,
                                               lu_b, ln1_g, ln1_b, msg_b,
                                               ln2_g, ln2_b, out1);
    bn_stats<<<391, 128, 0, stream>>>(out1, cat_b, stats);
    finalize<<<25000, 256, 0, stream>>>(out1, resid, stats, cat_b, bn_g, bn_b, inp_b,
                                        (float*)d_out);
    (void)attr_set;
}